// Round 1
// baseline (3927.352 us; speedup 1.0000x reference)
//
#include <hip/hip_runtime.h>
#include <stdint.h>

typedef short s16x8 __attribute__((ext_vector_type(8)));
typedef unsigned short u16x8 __attribute__((ext_vector_type(8)));
typedef float f32x4 __attribute__((ext_vector_type(4)));

__device__ __forceinline__ unsigned short f2bf(float f) {
    union { float f; unsigned u; } v; v.f = f;
    unsigned u = v.u;
    unsigned r = u + 0x7fffu + ((u >> 16) & 1u);
    return (unsigned short)(r >> 16);
}
__device__ __forceinline__ float bf2f(unsigned short h) {
    union { unsigned u; float f; } v; v.u = ((unsigned)h) << 16;
    return v.f;
}

// ---------------------------------------------------------------------------
// K0: weight repack (fp32 OIHW -> bf16 [kpos][oc][ic]), d5w -> bf16
// ---------------------------------------------------------------------------
__global__ void k0_prep(const float* __restrict__ c2w, const float* __restrict__ c3w,
                        const float* __restrict__ c4w, const float* __restrict__ d5w,
                        unsigned short* __restrict__ w2, unsigned short* __restrict__ w3,
                        unsigned short* __restrict__ w4, unsigned short* __restrict__ w5) {
    int t = blockIdx.x * 256 + threadIdx.x;
    if (t < 18432) {            // w2 [9][64][32] <- c2w [64][32][3][3]
        int kpos = t / 2048, rem = t % 2048, oc = rem / 32, ic = rem % 32;
        w2[t] = f2bf(c2w[(oc * 32 + ic) * 9 + kpos]);
        return;
    }
    t -= 18432;
    if (t < 36864) {            // w3 [9][64][64] <- c3w [64][64][3][3]
        int kpos = t / 4096, rem = t % 4096, oc = rem / 64, ic = rem % 64;
        w3[t] = f2bf(c3w[(oc * 64 + ic) * 9 + kpos]);
        return;
    }
    t -= 36864;
    if (t < 32768) {            // w4 [4][128][64] <- c4w [128][64][2][2]
        int kpos = t / 8192, rem = t % 8192, oc = rem / 64, ic = rem % 64;
        w4[t] = f2bf(c4w[(oc * 64 + ic) * 4 + kpos]);
        return;
    }
    t -= 32768;
    if (t < 294912) w5[t] = f2bf(d5w[t]);   // [256][1152] bf16
}

// ---------------------------------------------------------------------------
// K1: conv1 3x3 (3->32) + PReLU + maxpool 3x3 s2 ceil  -> p1 bf16 [n][23][23][32]
// fp32 VALU, block = 1 image, 8 strips of 4 output channels
// ---------------------------------------------------------------------------
__global__ __launch_bounds__(256, 2)
void k1_conv1(const float* __restrict__ x, const float* __restrict__ c1w,
              const float* __restrict__ c1b, const float* __restrict__ a1,
              unsigned short* __restrict__ p1) {
    __shared__ float xs[6912 + 16];            // [3][48][48] + OOB pad
    __shared__ float wp[864];                  // [8 strips][27 k][4 cl]
    __shared__ unsigned short cb[4 * 46 * 48]; // strip conv buf [4][46][48] bf16 (48-pad for b128)

    const int n = blockIdx.x, tid = threadIdx.x;

    const float4* xsrc = (const float4*)(x + n * 6912);
    for (int t = tid; t < 1728; t += 256) ((float4*)xs)[t] = xsrc[t];
    for (int t = tid; t < 864; t += 256) {
        int s = t / 108, r = t % 108, k = r >> 2, cl = r & 3;
        wp[t] = c1w[(s * 4 + cl) * 27 + k];
    }
    __syncthreads();

    for (int s = 0; s < 8; ++s) {
        // weights for this strip into registers: wr[k] = (cl0,cl1,cl2,cl3)
        float4 wr[27];
        #pragma unroll
        for (int k = 0; k < 27; ++k) wr[k] = *(const float4*)&wp[s * 108 + k * 4];
        float bias[4], alp[4];
        #pragma unroll
        for (int cl = 0; cl < 4; ++cl) { bias[cl] = c1b[s * 4 + cl]; alp[cl] = a1[s * 4 + cl]; }

        // phase A: conv+prelu for 4 channels, 4-px quads
        for (int q = tid; q < 552; q += 256) {
            int oy = q / 12, ox0 = (q % 12) * 4;
            float acc[4][4] = {};
            #pragma unroll
            for (int ic = 0; ic < 3; ++ic)
            #pragma unroll
            for (int ky = 0; ky < 3; ++ky) {
                const float* rp = &xs[(ic * 48 + oy + ky) * 48 + ox0];
                float4 A = *(const float4*)rp;
                float4 B = *(const float4*)(rp + 4);
                float v[8] = {A.x, A.y, A.z, A.w, B.x, B.y, B.z, B.w};
                #pragma unroll
                for (int kx = 0; kx < 3; ++kx) {
                    float4 w4 = wr[ic * 9 + ky * 3 + kx];
                    #pragma unroll
                    for (int j = 0; j < 4; ++j) {
                        float xv = v[kx + j];
                        acc[0][j] += xv * w4.x; acc[1][j] += xv * w4.y;
                        acc[2][j] += xv * w4.z; acc[3][j] += xv * w4.w;
                    }
                }
            }
            #pragma unroll
            for (int cl = 0; cl < 4; ++cl)
            #pragma unroll
            for (int j = 0; j < 4; ++j) {
                int ox = ox0 + j;
                if (ox < 46) {
                    float val = acc[cl][j] + bias[cl];
                    val = val >= 0.f ? val : val * alp[cl];
                    cb[(cl * 46 + oy) * 48 + ox] = f2bf(val);
                }
            }
        }
        __syncthreads();

        // phase B: 3x3 s2 ceil maxpool (pad=1 right/bottom == clip), 4 outputs/task
        for (int t = tid; t < 552; t += 256) {
            int cl = t / 138, r = t % 138, py = r / 6, px0 = (r % 6) * 4;
            int c0 = px0 * 2;
            float m[4] = {-3e38f, -3e38f, -3e38f, -3e38f};
            #pragma unroll
            for (int ky = 0; ky < 3; ++ky) {
                int y = py * 2 + ky;
                if (y < 46) {
                    const u16x8* rp = (const u16x8*)&cb[(cl * 46 + y) * 48 + c0];
                    u16x8 f0 = rp[0], f1 = rp[1];
                    float f[10];
                    #pragma unroll
                    for (int j = 0; j < 8; ++j) f[j] = bf2f(f0[j]);
                    f[8] = bf2f(f1[0]); f[9] = bf2f(f1[1]);
                    #pragma unroll
                    for (int j = 0; j < 4; ++j)
                    #pragma unroll
                    for (int kx = 0; kx < 3; ++kx) {
                        int col = c0 + 2 * j + kx;
                        if (col < 46) m[j] = fmaxf(m[j], f[2 * j + kx]);
                    }
                }
            }
            #pragma unroll
            for (int j = 0; j < 4; ++j) {
                int px = px0 + j;
                if (px < 23)
                    p1[n * 16928 + (py * 23 + px) * 32 + s * 4 + cl] = f2bf(m[j]);
            }
        }
        __syncthreads();
    }
}

// ---------------------------------------------------------------------------
// K2a: conv2 3x3 (32->64) + PReLU via MFMA 16x16x32 bf16
// M=441(pad448) px, N=64 oc, K=288 (9 chunks: k = kpos*32 + ic)
// ---------------------------------------------------------------------------
__global__ __launch_bounds__(256, 1)
void k2_conv2(const unsigned short* __restrict__ p1, const unsigned short* __restrict__ w2,
              const float* __restrict__ c2b, const float* __restrict__ a2,
              unsigned short* __restrict__ c2buf) {
    __shared__ unsigned short xs[16928];       // [23*23][32] channels-last bf16
    const int n = blockIdx.x, tid = threadIdx.x;

    const float4* src = (const float4*)(p1 + n * 16928);
    for (int t = tid; t < 2116; t += 256) ((float4*)xs)[t] = src[t];
    __syncthreads();

    const int w = tid >> 6, lane = tid & 63, q = lane >> 4, l16 = lane & 15;
    const int ic0 = q * 8;

    // preload all B fragments (9 kpos x 4 n-tiles) from global (L2-hot)
    s16x8 Bf[36];
    #pragma unroll
    for (int kp = 0; kp < 9; ++kp)
    #pragma unroll
    for (int nt = 0; nt < 4; ++nt) {
        int oc = nt * 16 + l16;
        Bf[kp * 4 + nt] = *(const s16x8*)(w2 + (kp * 64 + oc) * 32 + ic0);
    }

    for (int i = 0; i < 7; ++i) {
        int Mt = w * 7 + i;
        int m = Mt * 16 + l16;
        int px = m < 441 ? m : 440;
        int oy = px / 21, ox = px % 21;
        f32x4 z = {0.f, 0.f, 0.f, 0.f};
        f32x4 acc[4];
        #pragma unroll
        for (int nt = 0; nt < 4; ++nt) acc[nt] = z;

        #pragma unroll
        for (int kp = 0; kp < 9; ++kp) {
            int ky = kp / 3, kx = kp % 3;
            s16x8 A = *(const s16x8*)(xs + ((oy + ky) * 23 + ox + kx) * 32 + ic0);
            #pragma unroll
            for (int nt = 0; nt < 4; ++nt)
                acc[nt] = __builtin_amdgcn_mfma_f32_16x16x32_bf16(A, Bf[kp * 4 + nt], acc[nt], 0, 0, 0);
        }
        #pragma unroll
        for (int nt = 0; nt < 4; ++nt) {
            int oc = nt * 16 + l16;
            float bias = c2b[oc], al = a2[oc];
            #pragma unroll
            for (int r = 0; r < 4; ++r) {
                int row = Mt * 16 + q * 4 + r;
                if (row < 441) {
                    float val = acc[nt][r] + bias;
                    val = val >= 0.f ? val : val * al;
                    c2buf[(unsigned)n * 28672u + (unsigned)(row * 64 + oc)] = f2bf(val);
                }
            }
        }
    }
}

// ---------------------------------------------------------------------------
// K2b: maxpool 3x3 s2 (21->10, no pad needed) -> p2 bf16 [n][10][10][64]
// ---------------------------------------------------------------------------
__global__ void k2_pool(const unsigned short* __restrict__ c2buf, unsigned short* __restrict__ p2) {
    const int n = blockIdx.x, tid = threadIdx.x;
    const unsigned short* cbp = c2buf + (unsigned)n * 28672u;
    for (int t = tid; t < 6400; t += 256) {
        int oc = t & 63, r = t >> 6, py = r / 10, pxo = r % 10;
        float m = -3e38f;
        #pragma unroll
        for (int ky = 0; ky < 3; ++ky)
        #pragma unroll
        for (int kx = 0; kx < 3; ++kx)
            m = fmaxf(m, bf2f(cbp[((py * 2 + ky) * 21 + pxo * 2 + kx) * 64 + oc]));
        p2[(unsigned)n * 6400u + t] = f2bf(m);
    }
}

// ---------------------------------------------------------------------------
// K3: conv3 3x3 (64->64)+PReLU (MFMA) -> pool 2x2 -> conv4 2x2 (64->128)+PReLU
//     (MFMA) -> permuted flatten -> flat bf16 [n][1152]
// ---------------------------------------------------------------------------
__global__ __launch_bounds__(256, 2)
void k3_conv34(const unsigned short* __restrict__ p2, const unsigned short* __restrict__ w3,
               const float* __restrict__ c3b, const float* __restrict__ a3,
               const unsigned short* __restrict__ w4, const float* __restrict__ c4b,
               const float* __restrict__ a4, unsigned short* __restrict__ flat) {
    __shared__ unsigned short xs[6400];     // [10*10][64]
    __shared__ unsigned short c3buf[4096];  // [64 px][64 oc]
    __shared__ unsigned short p3[1024];     // [4*4][64]
    const int n = blockIdx.x, tid = threadIdx.x;

    const float4* src = (const float4*)(p2 + n * 6400);
    for (int t = tid; t < 800; t += 256) ((float4*)xs)[t] = src[t];
    __syncthreads();

    const int w = tid >> 6, lane = tid & 63, q = lane >> 4, l16 = lane & 15;

    // conv3: wave w = M-tile w (px = w*16 + l16 over 8x8); K=576: 18 chunks
    {
        int px = w * 16 + l16;
        int oy = px >> 3, ox = px & 7;
        s16x8 Af[18];
        #pragma unroll
        for (int c = 0; c < 18; ++c) {
            int kp = c >> 1, ky = kp / 3, kx = kp % 3;
            int ic0 = (c & 1) * 32 + q * 8;
            Af[c] = *(const s16x8*)(xs + ((oy + ky) * 10 + ox + kx) * 64 + ic0);
        }
        #pragma unroll
        for (int nt = 0; nt < 4; ++nt) {
            int oc = nt * 16 + l16;
            f32x4 acc = {0.f, 0.f, 0.f, 0.f};
            #pragma unroll
            for (int c = 0; c < 18; ++c) {
                int kp = c >> 1;
                int ic0 = (c & 1) * 32 + q * 8;
                s16x8 B = *(const s16x8*)(w3 + (kp * 64 + oc) * 64 + ic0);
                acc = __builtin_amdgcn_mfma_f32_16x16x32_bf16(Af[c], B, acc, 0, 0, 0);
            }
            float bias = c3b[oc], al = a3[oc];
            #pragma unroll
            for (int r = 0; r < 4; ++r) {
                int row = w * 16 + q * 4 + r;   // px 0..63
                float val = acc[r] + bias;
                val = val >= 0.f ? val : val * al;
                c3buf[row * 64 + oc] = f2bf(val);
            }
        }
    }
    __syncthreads();

    // pool3 2x2 s2 (8->4, exact)
    for (int t = tid; t < 1024; t += 256) {
        int oc = t & 63, r = t >> 6, py = r >> 2, pxo = r & 3;
        float m = -3e38f;
        #pragma unroll
        for (int ky = 0; ky < 2; ++ky)
        #pragma unroll
        for (int kx = 0; kx < 2; ++kx)
            m = fmaxf(m, bf2f(c3buf[((py * 2 + ky) * 8 + pxo * 2 + kx) * 64 + oc]));
        p3[t] = f2bf(m);
    }
    __syncthreads();

    // conv4: M=9(pad16) px, N=128 (wave w -> n-tiles w*2, w*2+1), K=256: 8 chunks
    {
        int m = l16, px = m < 9 ? m : 8;
        int oy = px / 3, ox = px % 3;
        s16x8 Af[8];
        #pragma unroll
        for (int c = 0; c < 8; ++c) {
            int kp = c >> 1, ky = kp >> 1, kx = kp & 1;
            int ic0 = (c & 1) * 32 + q * 8;
            Af[c] = *(const s16x8*)(p3 + ((oy + ky) * 4 + ox + kx) * 64 + ic0);
        }
        #pragma unroll
        for (int h = 0; h < 2; ++h) {
            int nt = w * 2 + h, oc = nt * 16 + l16;
            f32x4 acc = {0.f, 0.f, 0.f, 0.f};
            #pragma unroll
            for (int c = 0; c < 8; ++c) {
                int kp = c >> 1;
                int ic0 = (c & 1) * 32 + q * 8;
                s16x8 B = *(const s16x8*)(w4 + (kp * 128 + oc) * 64 + ic0);
                acc = __builtin_amdgcn_mfma_f32_16x16x32_bf16(Af[c], B, acc, 0, 0, 0);
            }
            float bias = c4b[oc], al = a4[oc];
            #pragma unroll
            for (int r = 0; r < 4; ++r) {
                int row = q * 4 + r;
                if (row < 9) {
                    int hy = row / 3, wx = row % 3;
                    float val = acc[r] + bias;
                    val = val >= 0.f ? val : val * al;
                    // torch permute(0,3,2,1).view: idx = (wx*3 + hy)*128 + oc
                    flat[(unsigned)n * 1152u + (wx * 3 + hy) * 128 + oc] = f2bf(val);
                }
            }
        }
    }
}

// ---------------------------------------------------------------------------
// K5: d5 GEMM (MFMA, K split across 4 waves) + bias + PReLU, then 3 heads
// (fp32 dots) + 2-class softmax. Output: b[2048x4] | c[2048x10] | a[2048x2]
// ---------------------------------------------------------------------------
__global__ __launch_bounds__(256, 1)
void k5_head(const unsigned short* __restrict__ flat, const unsigned short* __restrict__ w5,
             const float* __restrict__ d5b, const float* __restrict__ a5,
             const float* __restrict__ d61w, const float* __restrict__ d61b,
             const float* __restrict__ d62w, const float* __restrict__ d62b,
             const float* __restrict__ d63w, const float* __restrict__ d63b,
             float* __restrict__ out) {
    __shared__ float hbuf[4 * 16 * 128];   // partial sums per wave (32 KB)
    __shared__ float hL[16 * 256];         // h after reduce+prelu (16 KB)
    __shared__ float lg[16 * 16];          // head logits
    const int blk = blockIdx.x, tid = threadIdx.x;
    const int w = tid >> 6, lane = tid & 63, q = lane >> 4, l16 = lane & 15;
    const int img = blk * 16 + l16;

    for (int rep = 0; rep < 2; ++rep) {    // two halves of the 256 outputs
        f32x4 z = {0.f, 0.f, 0.f, 0.f};
        f32x4 acc[8];
        #pragma unroll
        for (int nt = 0; nt < 8; ++nt) acc[nt] = z;

        for (int cc = 0; cc < 9; ++cc) {   // this wave's K quarter
            int c = w * 9 + cc;
            int k0 = c * 32 + q * 8;
            s16x8 A = *(const s16x8*)(flat + (unsigned)img * 1152u + k0);
            #pragma unroll
            for (int nt = 0; nt < 8; ++nt) {
                int oc = (rep * 8 + nt) * 16 + l16;
                s16x8 B = *(const s16x8*)(w5 + (unsigned)oc * 1152u + k0);
                acc[nt] = __builtin_amdgcn_mfma_f32_16x16x32_bf16(A, B, acc[nt], 0, 0, 0);
            }
        }
        #pragma unroll
        for (int nt = 0; nt < 8; ++nt)
        #pragma unroll
        for (int r = 0; r < 4; ++r) {
            int row = q * 4 + r;           // image within tile
            hbuf[(w * 16 + row) * 128 + nt * 16 + l16] = acc[nt][r];
        }
        __syncthreads();
        for (int t = tid; t < 2048; t += 256) {
            int oc_h = t & 127, im = t >> 7;
            float s = hbuf[im * 128 + oc_h] + hbuf[(16 + im) * 128 + oc_h]
                    + hbuf[(32 + im) * 128 + oc_h] + hbuf[(48 + im) * 128 + oc_h];
            int oc = rep * 128 + oc_h;
            s += d5b[oc];
            s = s >= 0.f ? s : s * a5[oc];
            hL[im * 256 + oc] = s;
        }
        __syncthreads();
    }

    // heads: thread = (img 0..15, out 0..15); fp32
    {
        int im = tid >> 4, o = tid & 15;
        const float* wrow; float bias;
        if (o < 2)      { wrow = d61w + o * 256;       bias = d61b[o]; }
        else if (o < 6) { wrow = d62w + (o - 2) * 256; bias = d62b[o - 2]; }
        else            { wrow = d63w + (o - 6) * 256; bias = d63b[o - 6]; }
        float s = bias;
        for (int k = 0; k < 256; ++k) s += hL[im * 256 + k] * wrow[k];
        lg[im * 16 + o] = s;
    }
    __syncthreads();
    {
        int im = tid >> 4, o = tid & 15;
        int gimg = blk * 16 + im;
        float v = lg[im * 16 + o];
        if (o >= 2 && o < 6) {
            out[gimg * 4 + (o - 2)] = v;                       // b [N,4]
        } else if (o >= 6) {
            out[8192 + gimg * 10 + (o - 6)] = v;               // c [N,10]
        } else {
            float l0 = lg[im * 16 + 0], l1 = lg[im * 16 + 1];
            float mx = fmaxf(l0, l1);
            float e0 = __expf(l0 - mx), e1 = __expf(l1 - mx);
            out[28672 + gimg * 2 + o] = (o == 0 ? e0 : e1) / (e0 + e1);   // a [N,2]
        }
    }
}

// ---------------------------------------------------------------------------
extern "C" void kernel_launch(void* const* d_in, const int* in_sizes, int n_in,
                              void* d_out, int out_size, void* d_ws, size_t ws_size,
                              hipStream_t stream) {
    (void)in_sizes; (void)n_in; (void)out_size; (void)ws_size;
    const float* x    = (const float*)d_in[0];
    const float* c1w  = (const float*)d_in[1];
    const float* c1b  = (const float*)d_in[2];
    const float* a1   = (const float*)d_in[3];
    const float* c2w  = (const float*)d_in[4];
    const float* c2b  = (const float*)d_in[5];
    const float* a2   = (const float*)d_in[6];
    const float* c3w  = (const float*)d_in[7];
    const float* c3b  = (const float*)d_in[8];
    const float* a3   = (const float*)d_in[9];
    const float* c4w  = (const float*)d_in[10];
    const float* c4b  = (const float*)d_in[11];
    const float* a4   = (const float*)d_in[12];
    const float* d5w  = (const float*)d_in[13];
    const float* d5b  = (const float*)d_in[14];
    const float* a5   = (const float*)d_in[15];
    const float* d61w = (const float*)d_in[16];
    const float* d61b = (const float*)d_in[17];
    const float* d62w = (const float*)d_in[18];
    const float* d62b = (const float*)d_in[19];
    const float* d63w = (const float*)d_in[20];
    const float* d63b = (const float*)d_in[21];

    char* ws = (char*)d_ws;
    // region plan (aliasing by lifetime):
    //   p1    @ 0          : 69,337,088 B   (dead after K2a)
    //   c2buf @ 69,337,088 : 117,440,512 B  (dead after K2b)
    //   p2    @ 0          : 26,214,400 B   (aliases dead p1)
    //   flat  @ 26,214,400 : 4,718,592 B
    //   weights @ 186,777,600 : ~766 KB     -> total ~179 MB
    unsigned short* p1    = (unsigned short*)(ws + 0);
    unsigned short* c2buf = (unsigned short*)(ws + 69337088);
    unsigned short* p2    = (unsigned short*)(ws + 0);
    unsigned short* flat  = (unsigned short*)(ws + 26214400);
    unsigned short* w2    = (unsigned short*)(ws + 186777600);
    unsigned short* w3    = (unsigned short*)(ws + 186814464);
    unsigned short* w4    = (unsigned short*)(ws + 186888192);
    unsigned short* w5    = (unsigned short*)(ws + 186953728);

    k0_prep <<<1496, 256, 0, stream>>>(c2w, c3w, c4w, d5w, w2, w3, w4, w5);
    k1_conv1<<<2048, 256, 0, stream>>>(x, c1w, c1b, a1, p1);
    k2_conv2<<<2048, 256, 0, stream>>>(p1, w2, c2b, a2, c2buf);
    k2_pool <<<2048, 256, 0, stream>>>(c2buf, p2);
    k3_conv34<<<2048, 256, 0, stream>>>(p2, w3, c3b, a3, w4, c4b, a4, flat);
    k5_head <<<128, 256, 0, stream>>>(flat, w5, d5b, a5, d61w, d61b, d62w, d62b,
                                      d63w, d63b, (float*)d_out);
}

// Round 2
// 594.487 us; speedup vs baseline: 6.6063x; 6.6063x over previous
//
#include <hip/hip_runtime.h>
#include <stdint.h>

typedef short s16x8 __attribute__((ext_vector_type(8)));
typedef unsigned short u16x8 __attribute__((ext_vector_type(8)));
typedef float f32x4 __attribute__((ext_vector_type(4)));

__device__ __forceinline__ unsigned short f2bf(float f) {
    union { float f; unsigned u; } v; v.f = f;
    unsigned u = v.u;
    unsigned r = u + 0x7fffu + ((u >> 16) & 1u);
    return (unsigned short)(r >> 16);
}
__device__ __forceinline__ float bf2f(unsigned short h) {
    union { unsigned u; float f; } v; v.u = ((unsigned)h) << 16;
    return v.f;
}

// ---------------------------------------------------------------------------
// K0: weight repack (fp32 OIHW -> bf16 [kpos][oc][ic]), d5w -> bf16
// ---------------------------------------------------------------------------
__global__ void k0_prep(const float* __restrict__ c2w, const float* __restrict__ c3w,
                        const float* __restrict__ c4w, const float* __restrict__ d5w,
                        unsigned short* __restrict__ w2, unsigned short* __restrict__ w3,
                        unsigned short* __restrict__ w4, unsigned short* __restrict__ w5) {
    int t = blockIdx.x * 256 + threadIdx.x;
    if (t < 18432) {            // w2 [9][64][32] <- c2w [64][32][3][3]
        int kpos = t / 2048, rem = t % 2048, oc = rem / 32, ic = rem % 32;
        w2[t] = f2bf(c2w[(oc * 32 + ic) * 9 + kpos]);
        return;
    }
    t -= 18432;
    if (t < 36864) {            // w3 [9][64][64] <- c3w [64][64][3][3]
        int kpos = t / 4096, rem = t % 4096, oc = rem / 64, ic = rem % 64;
        w3[t] = f2bf(c3w[(oc * 64 + ic) * 9 + kpos]);
        return;
    }
    t -= 36864;
    if (t < 32768) {            // w4 [4][128][64] <- c4w [128][64][2][2]
        int kpos = t / 8192, rem = t % 8192, oc = rem / 64, ic = rem % 64;
        w4[t] = f2bf(c4w[(oc * 64 + ic) * 4 + kpos]);
        return;
    }
    t -= 32768;
    if (t < 294912) w5[t] = f2bf(d5w[t]);   // [256][1152] bf16
}

// ---------------------------------------------------------------------------
// K1 (MFMA rewrite): conv1 3x3 (3->32) + PReLU + maxpool 3x3 s2 ceil
//   -> p1 bf16 [n][23][23][32]
// Implicit-GEMM: M = strip pixels, N = 32 oc, K = 27 (ic*9+ky*3+kx) pad 32.
// x staged as split hi+lo bf16 (keeps fp32 input precision; 2 MFMAs/B-tile).
// 4 strips of 6 pool rows; conv strip buffer in LDS (+1-short row pad to
// break the q-group 4-way bank conflict on epilogue writes).
// Register footprint ~50 VGPRs (R1's float4 wr[27] spilled -> 6.9GB scratch
// traffic; this eliminates it).
// ---------------------------------------------------------------------------
__global__ __launch_bounds__(256, 2)
void k1_conv1(const float* __restrict__ x, const float* __restrict__ c1w,
              const float* __restrict__ c1b, const float* __restrict__ a1,
              unsigned short* __restrict__ p1) {
    __shared__ unsigned short xhl[2 * 6912];     // [3][48][48][2] hi,lo interleaved (27.6 KB)
    __shared__ unsigned short wlds[1024];        // [32 oc][32 k], k>=27 zero     (2 KB)
    __shared__ unsigned short cbuf[598 * 33];    // [13*46 px][32 oc +1 pad]      (39.5 KB)
    __shared__ float bls[32], als[32];

    const int n = blockIdx.x, tid = threadIdx.x;

    // stage x as hi/lo bf16 split
    for (int t = tid; t < 6912; t += 256) {
        float f = x[n * 6912 + t];
        unsigned short h = f2bf(f);
        unsigned short l = f2bf(f - bf2f(h));
        xhl[2 * t]     = h;
        xhl[2 * t + 1] = l;
    }
    // stage weights [oc][k], zero-pad k 27..31
    for (int t = tid; t < 1024; t += 256) {
        int oc = t >> 5, k = t & 31;
        wlds[t] = (k < 27) ? f2bf(c1w[oc * 27 + k]) : (unsigned short)0;
    }
    if (tid < 32) { bls[tid] = c1b[tid]; als[tid] = a1[tid]; }
    __syncthreads();

    const int w = tid >> 6, lane = tid & 63, q = lane >> 4, l16 = lane & 15;

    // B fragments: oc = nt*16+l16, k = q*8..q*8+7 (contiguous b128)
    s16x8 Bf[2];
    #pragma unroll
    for (int nt = 0; nt < 2; ++nt)
        Bf[nt] = *(const s16x8*)(wlds + (nt * 16 + l16) * 32 + q * 8);

    for (int s = 0; s < 4; ++s) {
        const int py0 = s * 6;
        const int cy0 = py0 * 2;
        const int nrows = (46 - cy0) < 13 ? (46 - cy0) : 13;   // 13,13,13,10
        const int P = nrows * 46;
        const int ntiles = (P + 15) >> 4;
        const int nprows = (23 - py0) < 6 ? (23 - py0) : 6;    // 6,6,6,5

        // conv via MFMA
        for (int T = w; T < ntiles; T += 4) {
            int m = T * 16 + l16;
            int p = m < P ? m : P - 1;
            int ry = p / 46, ox = p - ry * 46;
            int cy = cy0 + ry;
            s16x8 Ah, Al;
            #pragma unroll
            for (int j = 0; j < 8; ++j) {
                int k = q * 8 + j;
                int kk = k < 27 ? k : 26;            // k>=27: B is zero, value irrelevant
                int ic = kk / 9, r9 = kk - ic * 9, ky = r9 / 3, kx = r9 - ky * 3;
                unsigned v = *(const unsigned*)&xhl[2 * (ic * 2304 + (cy + ky) * 48 + ox + kx)];
                Ah[j] = (short)(v & 0xffffu);
                Al[j] = (short)(v >> 16);
            }
            f32x4 acc[2] = {{0.f,0.f,0.f,0.f},{0.f,0.f,0.f,0.f}};
            #pragma unroll
            for (int nt = 0; nt < 2; ++nt) {
                acc[nt] = __builtin_amdgcn_mfma_f32_16x16x32_bf16(Ah, Bf[nt], acc[nt], 0, 0, 0);
                acc[nt] = __builtin_amdgcn_mfma_f32_16x16x32_bf16(Al, Bf[nt], acc[nt], 0, 0, 0);
            }
            #pragma unroll
            for (int nt = 0; nt < 2; ++nt) {
                int oc = nt * 16 + l16;
                float bias = bls[oc], al = als[oc];
                #pragma unroll
                for (int r = 0; r < 4; ++r) {
                    int row = T * 16 + q * 4 + r;
                    if (row < P) {
                        float val = acc[nt][r] + bias;
                        val = val >= 0.f ? val : val * al;
                        cbuf[row * 33 + oc] = f2bf(val);
                    }
                }
            }
        }
        __syncthreads();

        // pool 3x3 s2 ceil over this strip
        int ntask = nprows * 736;                 // nprows * 23 * 32
        for (int t = tid; t < ntask; t += 256) {
            int py_l = t / 736; int rem = t - py_l * 736;
            int px = rem >> 5, oc = rem & 31;
            float mx = -3e38f;
            int ry0 = 2 * py_l, cx0 = 2 * px;
            #pragma unroll
            for (int ky = 0; ky < 3; ++ky) {
                int ry = ry0 + ky;
                if (ry < nrows) {
                    #pragma unroll
                    for (int kx = 0; kx < 3; ++kx) {
                        int cx = cx0 + kx;
                        if (cx < 46)
                            mx = fmaxf(mx, bf2f(cbuf[(ry * 46 + cx) * 33 + oc]));
                    }
                }
            }
            int py = py0 + py_l;
            p1[n * 16928 + (py * 23 + px) * 32 + oc] = f2bf(mx);
        }
        __syncthreads();
    }
}

// ---------------------------------------------------------------------------
// K2a: conv2 3x3 (32->64) + PReLU via MFMA 16x16x32 bf16
// M=441(pad448) px, N=64 oc, K=288 (9 chunks: k = kpos*32 + ic)
// ---------------------------------------------------------------------------
__global__ __launch_bounds__(256, 1)
void k2_conv2(const unsigned short* __restrict__ p1, const unsigned short* __restrict__ w2,
              const float* __restrict__ c2b, const float* __restrict__ a2,
              unsigned short* __restrict__ c2buf) {
    __shared__ unsigned short xs[16928];       // [23*23][32] channels-last bf16
    const int n = blockIdx.x, tid = threadIdx.x;

    const float4* src = (const float4*)(p1 + n * 16928);
    for (int t = tid; t < 2116; t += 256) ((float4*)xs)[t] = src[t];
    __syncthreads();

    const int w = tid >> 6, lane = tid & 63, q = lane >> 4, l16 = lane & 15;
    const int ic0 = q * 8;

    // preload all B fragments (9 kpos x 4 n-tiles) from global (L2-hot)
    s16x8 Bf[36];
    #pragma unroll
    for (int kp = 0; kp < 9; ++kp)
    #pragma unroll
    for (int nt = 0; nt < 4; ++nt) {
        int oc = nt * 16 + l16;
        Bf[kp * 4 + nt] = *(const s16x8*)(w2 + (kp * 64 + oc) * 32 + ic0);
    }

    for (int i = 0; i < 7; ++i) {
        int Mt = w * 7 + i;
        int m = Mt * 16 + l16;
        int px = m < 441 ? m : 440;
        int oy = px / 21, ox = px % 21;
        f32x4 z = {0.f, 0.f, 0.f, 0.f};
        f32x4 acc[4];
        #pragma unroll
        for (int nt = 0; nt < 4; ++nt) acc[nt] = z;

        #pragma unroll
        for (int kp = 0; kp < 9; ++kp) {
            int ky = kp / 3, kx = kp % 3;
            s16x8 A = *(const s16x8*)(xs + ((oy + ky) * 23 + ox + kx) * 32 + ic0);
            #pragma unroll
            for (int nt = 0; nt < 4; ++nt)
                acc[nt] = __builtin_amdgcn_mfma_f32_16x16x32_bf16(A, Bf[kp * 4 + nt], acc[nt], 0, 0, 0);
        }
        #pragma unroll
        for (int nt = 0; nt < 4; ++nt) {
            int oc = nt * 16 + l16;
            float bias = c2b[oc], al = a2[oc];
            #pragma unroll
            for (int r = 0; r < 4; ++r) {
                int row = Mt * 16 + q * 4 + r;
                if (row < 441) {
                    float val = acc[nt][r] + bias;
                    val = val >= 0.f ? val : val * al;
                    c2buf[(unsigned)n * 28672u + (unsigned)(row * 64 + oc)] = f2bf(val);
                }
            }
        }
    }
}

// ---------------------------------------------------------------------------
// K2b: maxpool 3x3 s2 (21->10, no pad needed) -> p2 bf16 [n][10][10][64]
// ---------------------------------------------------------------------------
__global__ void k2_pool(const unsigned short* __restrict__ c2buf, unsigned short* __restrict__ p2) {
    const int n = blockIdx.x, tid = threadIdx.x;
    const unsigned short* cbp = c2buf + (unsigned)n * 28672u;
    for (int t = tid; t < 6400; t += 256) {
        int oc = t & 63, r = t >> 6, py = r / 10, pxo = r % 10;
        float m = -3e38f;
        #pragma unroll
        for (int ky = 0; ky < 3; ++ky)
        #pragma unroll
        for (int kx = 0; kx < 3; ++kx)
            m = fmaxf(m, bf2f(cbp[((py * 2 + ky) * 21 + pxo * 2 + kx) * 64 + oc]));
        p2[(unsigned)n * 6400u + t] = f2bf(m);
    }
}

// ---------------------------------------------------------------------------
// K3: conv3 3x3 (64->64)+PReLU (MFMA) -> pool 2x2 -> conv4 2x2 (64->128)+PReLU
//     (MFMA) -> permuted flatten -> flat bf16 [n][1152]
// ---------------------------------------------------------------------------
__global__ __launch_bounds__(256, 2)
void k3_conv34(const unsigned short* __restrict__ p2, const unsigned short* __restrict__ w3,
               const float* __restrict__ c3b, const float* __restrict__ a3,
               const unsigned short* __restrict__ w4, const float* __restrict__ c4b,
               const float* __restrict__ a4, unsigned short* __restrict__ flat) {
    __shared__ unsigned short xs[6400];     // [10*10][64]
    __shared__ unsigned short c3buf[4096];  // [64 px][64 oc]
    __shared__ unsigned short p3[1024];     // [4*4][64]
    const int n = blockIdx.x, tid = threadIdx.x;

    const float4* src = (const float4*)(p2 + n * 6400);
    for (int t = tid; t < 800; t += 256) ((float4*)xs)[t] = src[t];
    __syncthreads();

    const int w = tid >> 6, lane = tid & 63, q = lane >> 4, l16 = lane & 15;

    // conv3: wave w = M-tile w (px = w*16 + l16 over 8x8); K=576: 18 chunks
    {
        int px = w * 16 + l16;
        int oy = px >> 3, ox = px & 7;
        s16x8 Af[18];
        #pragma unroll
        for (int c = 0; c < 18; ++c) {
            int kp = c >> 1, ky = kp / 3, kx = kp % 3;
            int ic0 = (c & 1) * 32 + q * 8;
            Af[c] = *(const s16x8*)(xs + ((oy + ky) * 10 + ox + kx) * 64 + ic0);
        }
        #pragma unroll
        for (int nt = 0; nt < 4; ++nt) {
            int oc = nt * 16 + l16;
            f32x4 acc = {0.f, 0.f, 0.f, 0.f};
            #pragma unroll
            for (int c = 0; c < 18; ++c) {
                int kp = c >> 1;
                int ic0 = (c & 1) * 32 + q * 8;
                s16x8 B = *(const s16x8*)(w3 + (kp * 64 + oc) * 64 + ic0);
                acc = __builtin_amdgcn_mfma_f32_16x16x32_bf16(Af[c], B, acc, 0, 0, 0);
            }
            float bias = c3b[oc], al = a3[oc];
            #pragma unroll
            for (int r = 0; r < 4; ++r) {
                int row = w * 16 + q * 4 + r;   // px 0..63
                float val = acc[r] + bias;
                val = val >= 0.f ? val : val * al;
                c3buf[row * 64 + oc] = f2bf(val);
            }
        }
    }
    __syncthreads();

    // pool3 2x2 s2 (8->4, exact)
    for (int t = tid; t < 1024; t += 256) {
        int oc = t & 63, r = t >> 6, py = r >> 2, pxo = r & 3;
        float m = -3e38f;
        #pragma unroll
        for (int ky = 0; ky < 2; ++ky)
        #pragma unroll
        for (int kx = 0; kx < 2; ++kx)
            m = fmaxf(m, bf2f(c3buf[((py * 2 + ky) * 8 + pxo * 2 + kx) * 64 + oc]));
        p3[t] = f2bf(m);
    }
    __syncthreads();

    // conv4: M=9(pad16) px, N=128 (wave w -> n-tiles w*2, w*2+1), K=256: 8 chunks
    {
        int m = l16, px = m < 9 ? m : 8;
        int oy = px / 3, ox = px % 3;
        s16x8 Af[8];
        #pragma unroll
        for (int c = 0; c < 8; ++c) {
            int kp = c >> 1, ky = kp >> 1, kx = kp & 1;
            int ic0 = (c & 1) * 32 + q * 8;
            Af[c] = *(const s16x8*)(p3 + ((oy + ky) * 4 + ox + kx) * 64 + ic0);
        }
        #pragma unroll
        for (int h = 0; h < 2; ++h) {
            int nt = w * 2 + h, oc = nt * 16 + l16;
            f32x4 acc = {0.f, 0.f, 0.f, 0.f};
            #pragma unroll
            for (int c = 0; c < 8; ++c) {
                int kp = c >> 1;
                int ic0 = (c & 1) * 32 + q * 8;
                s16x8 B = *(const s16x8*)(w4 + (kp * 128 + oc) * 64 + ic0);
                acc = __builtin_amdgcn_mfma_f32_16x16x32_bf16(Af[c], B, acc, 0, 0, 0);
            }
            float bias = c4b[oc], al = a4[oc];
            #pragma unroll
            for (int r = 0; r < 4; ++r) {
                int row = q * 4 + r;
                if (row < 9) {
                    int hy = row / 3, wx = row % 3;
                    float val = acc[r] + bias;
                    val = val >= 0.f ? val : val * al;
                    // torch permute(0,3,2,1).view: idx = (wx*3 + hy)*128 + oc
                    flat[(unsigned)n * 1152u + (wx * 3 + hy) * 128 + oc] = f2bf(val);
                }
            }
        }
    }
}

// ---------------------------------------------------------------------------
// K5: d5 GEMM (MFMA, K split across 4 waves) + bias + PReLU, then 3 heads
// (fp32 dots) + 2-class softmax. Output: b[2048x4] | c[2048x10] | a[2048x2]
// ---------------------------------------------------------------------------
__global__ __launch_bounds__(256, 1)
void k5_head(const unsigned short* __restrict__ flat, const unsigned short* __restrict__ w5,
             const float* __restrict__ d5b, const float* __restrict__ a5,
             const float* __restrict__ d61w, const float* __restrict__ d61b,
             const float* __restrict__ d62w, const float* __restrict__ d62b,
             const float* __restrict__ d63w, const float* __restrict__ d63b,
             float* __restrict__ out) {
    __shared__ float hbuf[4 * 16 * 128];   // partial sums per wave (32 KB)
    __shared__ float hL[16 * 256];         // h after reduce+prelu (16 KB)
    __shared__ float lg[16 * 16];          // head logits
    const int blk = blockIdx.x, tid = threadIdx.x;
    const int w = tid >> 6, lane = tid & 63, q = lane >> 4, l16 = lane & 15;
    const int img = blk * 16 + l16;

    for (int rep = 0; rep < 2; ++rep) {    // two halves of the 256 outputs
        f32x4 z = {0.f, 0.f, 0.f, 0.f};
        f32x4 acc[8];
        #pragma unroll
        for (int nt = 0; nt < 8; ++nt) acc[nt] = z;

        for (int cc = 0; cc < 9; ++cc) {   // this wave's K quarter
            int c = w * 9 + cc;
            int k0 = c * 32 + q * 8;
            s16x8 A = *(const s16x8*)(flat + (unsigned)img * 1152u + k0);
            #pragma unroll
            for (int nt = 0; nt < 8; ++nt) {
                int oc = (rep * 8 + nt) * 16 + l16;
                s16x8 B = *(const s16x8*)(w5 + (unsigned)oc * 1152u + k0);
                acc[nt] = __builtin_amdgcn_mfma_f32_16x16x32_bf16(A, B, acc[nt], 0, 0, 0);
            }
        }
        #pragma unroll
        for (int nt = 0; nt < 8; ++nt)
        #pragma unroll
        for (int r = 0; r < 4; ++r) {
            int row = q * 4 + r;           // image within tile
            hbuf[(w * 16 + row) * 128 + nt * 16 + l16] = acc[nt][r];
        }
        __syncthreads();
        for (int t = tid; t < 2048; t += 256) {
            int oc_h = t & 127, im = t >> 7;
            float s = hbuf[im * 128 + oc_h] + hbuf[(16 + im) * 128 + oc_h]
                    + hbuf[(32 + im) * 128 + oc_h] + hbuf[(48 + im) * 128 + oc_h];
            int oc = rep * 128 + oc_h;
            s += d5b[oc];
            s = s >= 0.f ? s : s * a5[oc];
            hL[im * 256 + oc] = s;
        }
        __syncthreads();
    }

    // heads: thread = (img 0..15, out 0..15); fp32
    {
        int im = tid >> 4, o = tid & 15;
        const float* wrow; float bias;
        if (o < 2)      { wrow = d61w + o * 256;       bias = d61b[o]; }
        else if (o < 6) { wrow = d62w + (o - 2) * 256; bias = d62b[o - 2]; }
        else            { wrow = d63w + (o - 6) * 256; bias = d63b[o - 6]; }
        float s = bias;
        for (int k = 0; k < 256; ++k) s += hL[im * 256 + k] * wrow[k];
        lg[im * 16 + o] = s;
    }
    __syncthreads();
    {
        int im = tid >> 4, o = tid & 15;
        int gimg = blk * 16 + im;
        float v = lg[im * 16 + o];
        if (o >= 2 && o < 6) {
            out[gimg * 4 + (o - 2)] = v;                       // b [N,4]
        } else if (o >= 6) {
            out[8192 + gimg * 10 + (o - 6)] = v;               // c [N,10]
        } else {
            float l0 = lg[im * 16 + 0], l1 = lg[im * 16 + 1];
            float mx = fmaxf(l0, l1);
            float e0 = __expf(l0 - mx), e1 = __expf(l1 - mx);
            out[28672 + gimg * 2 + o] = (o == 0 ? e0 : e1) / (e0 + e1);   // a [N,2]
        }
    }
}

// ---------------------------------------------------------------------------
extern "C" void kernel_launch(void* const* d_in, const int* in_sizes, int n_in,
                              void* d_out, int out_size, void* d_ws, size_t ws_size,
                              hipStream_t stream) {
    (void)in_sizes; (void)n_in; (void)out_size; (void)ws_size;
    const float* x    = (const float*)d_in[0];
    const float* c1w  = (const float*)d_in[1];
    const float* c1b  = (const float*)d_in[2];
    const float* a1   = (const float*)d_in[3];
    const float* c2w  = (const float*)d_in[4];
    const float* c2b  = (const float*)d_in[5];
    const float* a2   = (const float*)d_in[6];
    const float* c3w  = (const float*)d_in[7];
    const float* c3b  = (const float*)d_in[8];
    const float* a3   = (const float*)d_in[9];
    const float* c4w  = (const float*)d_in[10];
    const float* c4b  = (const float*)d_in[11];
    const float* a4   = (const float*)d_in[12];
    const float* d5w  = (const float*)d_in[13];
    const float* d5b  = (const float*)d_in[14];
    const float* a5   = (const float*)d_in[15];
    const float* d61w = (const float*)d_in[16];
    const float* d61b = (const float*)d_in[17];
    const float* d62w = (const float*)d_in[18];
    const float* d62b = (const float*)d_in[19];
    const float* d63w = (const float*)d_in[20];
    const float* d63b = (const float*)d_in[21];

    char* ws = (char*)d_ws;
    // region plan (aliasing by lifetime):
    //   p1    @ 0          : 69,337,088 B   (dead after K2a)
    //   c2buf @ 69,337,088 : 117,440,512 B  (dead after K2b)
    //   p2    @ 0          : 26,214,400 B   (aliases dead p1)
    //   flat  @ 26,214,400 : 4,718,592 B
    //   weights @ 186,777,600 : ~766 KB     -> total ~179 MB
    unsigned short* p1    = (unsigned short*)(ws + 0);
    unsigned short* c2buf = (unsigned short*)(ws + 69337088);
    unsigned short* p2    = (unsigned short*)(ws + 0);
    unsigned short* flat  = (unsigned short*)(ws + 26214400);
    unsigned short* w2    = (unsigned short*)(ws + 186777600);
    unsigned short* w3    = (unsigned short*)(ws + 186814464);
    unsigned short* w4    = (unsigned short*)(ws + 186888192);
    unsigned short* w5    = (unsigned short*)(ws + 186953728);

    k0_prep <<<1496, 256, 0, stream>>>(c2w, c3w, c4w, d5w, w2, w3, w4, w5);
    k1_conv1<<<2048, 256, 0, stream>>>(x, c1w, c1b, a1, p1);
    k2_conv2<<<2048, 256, 0, stream>>>(p1, w2, c2b, a2, c2buf);
    k2_pool <<<2048, 256, 0, stream>>>(c2buf, p2);
    k3_conv34<<<2048, 256, 0, stream>>>(p2, w3, c3b, a3, w4, c4b, a4, flat);
    k5_head <<<128, 256, 0, stream>>>(flat, w5, d5b, a5, d61w, d61b, d62w, d62b,
                                      d63w, d63b, (float*)d_out);
}

// Round 3
// 585.831 us; speedup vs baseline: 6.7039x; 1.0148x over previous
//
#include <hip/hip_runtime.h>
#include <stdint.h>

typedef short s16x8 __attribute__((ext_vector_type(8)));
typedef unsigned short u16x8 __attribute__((ext_vector_type(8)));
typedef float f32x4 __attribute__((ext_vector_type(4)));

__device__ __forceinline__ unsigned short f2bf(float f) {
    union { float f; unsigned u; } v; v.f = f;
    unsigned u = v.u;
    unsigned r = u + 0x7fffu + ((u >> 16) & 1u);
    return (unsigned short)(r >> 16);
}
__device__ __forceinline__ float bf2f(unsigned short h) {
    union { unsigned u; float f; } v; v.u = ((unsigned)h) << 16;
    return v.f;
}

// ---------------------------------------------------------------------------
// K0: weight repack (fp32 OIHW -> bf16 [kpos][oc][ic]), d5w -> bf16
// ---------------------------------------------------------------------------
__global__ void k0_prep(const float* __restrict__ c2w, const float* __restrict__ c3w,
                        const float* __restrict__ c4w, const float* __restrict__ d5w,
                        unsigned short* __restrict__ w2, unsigned short* __restrict__ w3,
                        unsigned short* __restrict__ w4, unsigned short* __restrict__ w5) {
    int t = blockIdx.x * 256 + threadIdx.x;
    if (t < 18432) {            // w2 [9][64][32] <- c2w [64][32][3][3]
        int kpos = t / 2048, rem = t % 2048, oc = rem / 32, ic = rem % 32;
        w2[t] = f2bf(c2w[(oc * 32 + ic) * 9 + kpos]);
        return;
    }
    t -= 18432;
    if (t < 36864) {            // w3 [9][64][64] <- c3w [64][64][3][3]
        int kpos = t / 4096, rem = t % 4096, oc = rem / 64, ic = rem % 64;
        w3[t] = f2bf(c3w[(oc * 64 + ic) * 9 + kpos]);
        return;
    }
    t -= 36864;
    if (t < 32768) {            // w4 [4][128][64] <- c4w [128][64][2][2]
        int kpos = t / 8192, rem = t % 8192, oc = rem / 64, ic = rem % 64;
        w4[t] = f2bf(c4w[(oc * 64 + ic) * 4 + kpos]);
        return;
    }
    t -= 32768;
    if (t < 294912) w5[t] = f2bf(d5w[t]);   // [256][1152] bf16
}

// ---------------------------------------------------------------------------
// K1 (MFMA): conv1 3x3 (3->32) + PReLU + maxpool 3x3 s2 ceil
//   -> p1 bf16 [n][23][23][32]
// Implicit-GEMM: M = strip pixels, N = 32 oc, K = 27 (ic*9+ky*3+kx) pad 32.
// x staged as split hi+lo bf16 (keeps fp32 input precision; 2 MFMAs/B-tile).
// R3: gather offsets off[j] (k -> ic*2304+ky*48+kx) hoisted out of the tile
// loop — R2 recomputed the /9 and /3 magic-divides per j per tile (~60
// VALU/tile of pure index math; VALUBusy 47% @ MfmaUtil 2.6%).
// ---------------------------------------------------------------------------
__global__ __launch_bounds__(256, 2)
void k1_conv1(const float* __restrict__ x, const float* __restrict__ c1w,
              const float* __restrict__ c1b, const float* __restrict__ a1,
              unsigned short* __restrict__ p1) {
    __shared__ unsigned short xhl[2 * 6912];     // [3][48][48][2] hi,lo interleaved (27.6 KB)
    __shared__ unsigned short wlds[1024];        // [32 oc][32 k], k>=27 zero     (2 KB)
    __shared__ unsigned short cbuf[598 * 33];    // [13*46 px][32 oc +1 pad]      (39.5 KB)
    __shared__ float bls[32], als[32];

    const int n = blockIdx.x, tid = threadIdx.x;

    // stage x as hi/lo bf16 split
    for (int t = tid; t < 6912; t += 256) {
        float f = x[n * 6912 + t];
        unsigned short h = f2bf(f);
        unsigned short l = f2bf(f - bf2f(h));
        xhl[2 * t]     = h;
        xhl[2 * t + 1] = l;
    }
    // stage weights [oc][k], zero-pad k 27..31
    for (int t = tid; t < 1024; t += 256) {
        int oc = t >> 5, k = t & 31;
        wlds[t] = (k < 27) ? f2bf(c1w[oc * 27 + k]) : (unsigned short)0;
    }
    if (tid < 32) { bls[tid] = c1b[tid]; als[tid] = a1[tid]; }
    __syncthreads();

    const int w = tid >> 6, lane = tid & 63, q = lane >> 4, l16 = lane & 15;

    // per-lane invariant gather offsets: k = q*8+j -> (ic,ky,kx) -> element off
    int off[8];
    #pragma unroll
    for (int j = 0; j < 8; ++j) {
        int k = q * 8 + j;
        int kk = k < 27 ? k : 26;            // k>=27: B is zero, value irrelevant
        int ic = kk / 9, r9 = kk - ic * 9, ky = r9 / 3, kx = r9 - ky * 3;
        off[j] = ic * 2304 + ky * 48 + kx;
    }

    // B fragments: oc = nt*16+l16, k = q*8..q*8+7 (contiguous b128)
    s16x8 Bf[2];
    #pragma unroll
    for (int nt = 0; nt < 2; ++nt)
        Bf[nt] = *(const s16x8*)(wlds + (nt * 16 + l16) * 32 + q * 8);

    const float bias0 = bls[l16], al0 = als[l16];
    const float bias1 = bls[16 + l16], al1 = als[16 + l16];

    for (int s = 0; s < 4; ++s) {
        const int py0 = s * 6;
        const int cy0 = py0 * 2;
        const int nrows = (46 - cy0) < 13 ? (46 - cy0) : 13;   // 13,13,13,10
        const int P = nrows * 46;
        const int ntiles = (P + 15) >> 4;
        const int nprows = (23 - py0) < 6 ? (23 - py0) : 6;    // 6,6,6,5
        const int base0 = cy0 * 48;

        // conv via MFMA
        for (int T = w; T < ntiles; T += 4) {
            int m = T * 16 + l16;
            int p = m < P ? m : P - 1;
            int ry = p / 46, ox = p - ry * 46;
            int base = base0 + ry * 48 + ox;
            unsigned vv[8];
            #pragma unroll
            for (int j = 0; j < 8; ++j)
                vv[j] = *(const unsigned*)&xhl[2 * (base + off[j])];
            s16x8 Ah, Al;
            #pragma unroll
            for (int j = 0; j < 8; ++j) {
                Ah[j] = (short)(vv[j] & 0xffffu);
                Al[j] = (short)(vv[j] >> 16);
            }
            f32x4 acc[2] = {{0.f,0.f,0.f,0.f},{0.f,0.f,0.f,0.f}};
            #pragma unroll
            for (int nt = 0; nt < 2; ++nt) {
                acc[nt] = __builtin_amdgcn_mfma_f32_16x16x32_bf16(Ah, Bf[nt], acc[nt], 0, 0, 0);
                acc[nt] = __builtin_amdgcn_mfma_f32_16x16x32_bf16(Al, Bf[nt], acc[nt], 0, 0, 0);
            }
            int rowb = T * 16 + q * 4;
            #pragma unroll
            for (int r = 0; r < 4; ++r) {
                int row = rowb + r;
                if (row < P) {
                    float v0 = acc[0][r] + bias0;
                    v0 = v0 >= 0.f ? v0 : v0 * al0;
                    cbuf[row * 33 + l16] = f2bf(v0);
                    float v1 = acc[1][r] + bias1;
                    v1 = v1 >= 0.f ? v1 : v1 * al1;
                    cbuf[row * 33 + 16 + l16] = f2bf(v1);
                }
            }
        }
        __syncthreads();

        // pool 3x3 s2 ceil over this strip
        int ntask = nprows * 736;                 // nprows * 23 * 32
        for (int t = tid; t < ntask; t += 256) {
            int py_l = t / 736; int rem = t - py_l * 736;
            int px = rem >> 5, oc = rem & 31;
            float mx = -3e38f;
            int ry0 = 2 * py_l, cx0 = 2 * px;
            #pragma unroll
            for (int ky = 0; ky < 3; ++ky) {
                int ry = ry0 + ky;
                if (ry < nrows) {
                    #pragma unroll
                    for (int kx = 0; kx < 3; ++kx) {
                        int cx = cx0 + kx;
                        if (cx < 46)
                            mx = fmaxf(mx, bf2f(cbuf[(ry * 46 + cx) * 33 + oc]));
                    }
                }
            }
            int py = py0 + py_l;
            p1[n * 16928 + (py * 23 + px) * 32 + oc] = f2bf(mx);
        }
        __syncthreads();
    }
}

// ---------------------------------------------------------------------------
// K2a: conv2 3x3 (32->64) + PReLU via MFMA 16x16x32 bf16
// M=441(pad448) px, N=64 oc, K=288 (9 chunks: k = kpos*32 + ic)
// ---------------------------------------------------------------------------
__global__ __launch_bounds__(256, 1)
void k2_conv2(const unsigned short* __restrict__ p1, const unsigned short* __restrict__ w2,
              const float* __restrict__ c2b, const float* __restrict__ a2,
              unsigned short* __restrict__ c2buf) {
    __shared__ unsigned short xs[16928];       // [23*23][32] channels-last bf16
    const int n = blockIdx.x, tid = threadIdx.x;

    const float4* src = (const float4*)(p1 + n * 16928);
    for (int t = tid; t < 2116; t += 256) ((float4*)xs)[t] = src[t];
    __syncthreads();

    const int w = tid >> 6, lane = tid & 63, q = lane >> 4, l16 = lane & 15;
    const int ic0 = q * 8;

    // preload all B fragments (9 kpos x 4 n-tiles) from global (L2-hot)
    s16x8 Bf[36];
    #pragma unroll
    for (int kp = 0; kp < 9; ++kp)
    #pragma unroll
    for (int nt = 0; nt < 4; ++nt) {
        int oc = nt * 16 + l16;
        Bf[kp * 4 + nt] = *(const s16x8*)(w2 + (kp * 64 + oc) * 32 + ic0);
    }

    for (int i = 0; i < 7; ++i) {
        int Mt = w * 7 + i;
        int m = Mt * 16 + l16;
        int px = m < 441 ? m : 440;
        int oy = px / 21, ox = px % 21;
        f32x4 z = {0.f, 0.f, 0.f, 0.f};
        f32x4 acc[4];
        #pragma unroll
        for (int nt = 0; nt < 4; ++nt) acc[nt] = z;

        #pragma unroll
        for (int kp = 0; kp < 9; ++kp) {
            int ky = kp / 3, kx = kp % 3;
            s16x8 A = *(const s16x8*)(xs + ((oy + ky) * 23 + ox + kx) * 32 + ic0);
            #pragma unroll
            for (int nt = 0; nt < 4; ++nt)
                acc[nt] = __builtin_amdgcn_mfma_f32_16x16x32_bf16(A, Bf[kp * 4 + nt], acc[nt], 0, 0, 0);
        }
        #pragma unroll
        for (int nt = 0; nt < 4; ++nt) {
            int oc = nt * 16 + l16;
            float bias = c2b[oc], al = a2[oc];
            #pragma unroll
            for (int r = 0; r < 4; ++r) {
                int row = Mt * 16 + q * 4 + r;
                if (row < 441) {
                    float val = acc[nt][r] + bias;
                    val = val >= 0.f ? val : val * al;
                    c2buf[(unsigned)n * 28672u + (unsigned)(row * 64 + oc)] = f2bf(val);
                }
            }
        }
    }
}

// ---------------------------------------------------------------------------
// K2b: maxpool 3x3 s2 (21->10, no pad needed) -> p2 bf16 [n][10][10][64]
// ---------------------------------------------------------------------------
__global__ void k2_pool(const unsigned short* __restrict__ c2buf, unsigned short* __restrict__ p2) {
    const int n = blockIdx.x, tid = threadIdx.x;
    const unsigned short* cbp = c2buf + (unsigned)n * 28672u;
    for (int t = tid; t < 6400; t += 256) {
        int oc = t & 63, r = t >> 6, py = r / 10, pxo = r % 10;
        float m = -3e38f;
        #pragma unroll
        for (int ky = 0; ky < 3; ++ky)
        #pragma unroll
        for (int kx = 0; kx < 3; ++kx)
            m = fmaxf(m, bf2f(cbp[((py * 2 + ky) * 21 + pxo * 2 + kx) * 64 + oc]));
        p2[(unsigned)n * 6400u + t] = f2bf(m);
    }
}

// ---------------------------------------------------------------------------
// K3: conv3 3x3 (64->64)+PReLU (MFMA) -> pool 2x2 -> conv4 2x2 (64->128)+PReLU
//     (MFMA) -> permuted flatten -> flat bf16 [n][1152]
// ---------------------------------------------------------------------------
__global__ __launch_bounds__(256, 2)
void k3_conv34(const unsigned short* __restrict__ p2, const unsigned short* __restrict__ w3,
               const float* __restrict__ c3b, const float* __restrict__ a3,
               const unsigned short* __restrict__ w4, const float* __restrict__ c4b,
               const float* __restrict__ a4, unsigned short* __restrict__ flat) {
    __shared__ unsigned short xs[6400];     // [10*10][64]
    __shared__ unsigned short c3buf[4096];  // [64 px][64 oc]
    __shared__ unsigned short p3[1024];     // [4*4][64]
    const int n = blockIdx.x, tid = threadIdx.x;

    const float4* src = (const float4*)(p2 + n * 6400);
    for (int t = tid; t < 800; t += 256) ((float4*)xs)[t] = src[t];
    __syncthreads();

    const int w = tid >> 6, lane = tid & 63, q = lane >> 4, l16 = lane & 15;

    // conv3: wave w = M-tile w (px = w*16 + l16 over 8x8); K=576: 18 chunks
    {
        int px = w * 16 + l16;
        int oy = px >> 3, ox = px & 7;
        s16x8 Af[18];
        #pragma unroll
        for (int c = 0; c < 18; ++c) {
            int kp = c >> 1, ky = kp / 3, kx = kp % 3;
            int ic0 = (c & 1) * 32 + q * 8;
            Af[c] = *(const s16x8*)(xs + ((oy + ky) * 10 + ox + kx) * 64 + ic0);
        }
        #pragma unroll
        for (int nt = 0; nt < 4; ++nt) {
            int oc = nt * 16 + l16;
            f32x4 acc = {0.f, 0.f, 0.f, 0.f};
            #pragma unroll
            for (int c = 0; c < 18; ++c) {
                int kp = c >> 1;
                int ic0 = (c & 1) * 32 + q * 8;
                s16x8 B = *(const s16x8*)(w3 + (kp * 64 + oc) * 64 + ic0);
                acc = __builtin_amdgcn_mfma_f32_16x16x32_bf16(Af[c], B, acc, 0, 0, 0);
            }
            float bias = c3b[oc], al = a3[oc];
            #pragma unroll
            for (int r = 0; r < 4; ++r) {
                int row = w * 16 + q * 4 + r;   // px 0..63
                float val = acc[r] + bias;
                val = val >= 0.f ? val : val * al;
                c3buf[row * 64 + oc] = f2bf(val);
            }
        }
    }
    __syncthreads();

    // pool3 2x2 s2 (8->4, exact)
    for (int t = tid; t < 1024; t += 256) {
        int oc = t & 63, r = t >> 6, py = r >> 2, pxo = r & 3;
        float m = -3e38f;
        #pragma unroll
        for (int ky = 0; ky < 2; ++ky)
        #pragma unroll
        for (int kx = 0; kx < 2; ++kx)
            m = fmaxf(m, bf2f(c3buf[((py * 2 + ky) * 8 + pxo * 2 + kx) * 64 + oc]));
        p3[t] = f2bf(m);
    }
    __syncthreads();

    // conv4: M=9(pad16) px, N=128 (wave w -> n-tiles w*2, w*2+1), K=256: 8 chunks
    {
        int m = l16, px = m < 9 ? m : 8;
        int oy = px / 3, ox = px % 3;
        s16x8 Af[8];
        #pragma unroll
        for (int c = 0; c < 8; ++c) {
            int kp = c >> 1, ky = kp >> 1, kx = kp & 1;
            int ic0 = (c & 1) * 32 + q * 8;
            Af[c] = *(const s16x8*)(p3 + ((oy + ky) * 4 + ox + kx) * 64 + ic0);
        }
        #pragma unroll
        for (int h = 0; h < 2; ++h) {
            int nt = w * 2 + h, oc = nt * 16 + l16;
            f32x4 acc = {0.f, 0.f, 0.f, 0.f};
            #pragma unroll
            for (int c = 0; c < 8; ++c) {
                int kp = c >> 1;
                int ic0 = (c & 1) * 32 + q * 8;
                s16x8 B = *(const s16x8*)(w4 + (kp * 128 + oc) * 64 + ic0);
                acc = __builtin_amdgcn_mfma_f32_16x16x32_bf16(Af[c], B, acc, 0, 0, 0);
            }
            float bias = c4b[oc], al = a4[oc];
            #pragma unroll
            for (int r = 0; r < 4; ++r) {
                int row = q * 4 + r;
                if (row < 9) {
                    int hy = row / 3, wx = row % 3;
                    float val = acc[r] + bias;
                    val = val >= 0.f ? val : val * al;
                    // torch permute(0,3,2,1).view: idx = (wx*3 + hy)*128 + oc
                    flat[(unsigned)n * 1152u + (wx * 3 + hy) * 128 + oc] = f2bf(val);
                }
            }
        }
    }
}

// ---------------------------------------------------------------------------
// K5: d5 GEMM (MFMA, K split across 4 waves) + bias + PReLU, then 3 heads
// (fp32 dots) + 2-class softmax. Output: b[2048x4] | c[2048x10] | a[2048x2]
// ---------------------------------------------------------------------------
__global__ __launch_bounds__(256, 1)
void k5_head(const unsigned short* __restrict__ flat, const unsigned short* __restrict__ w5,
             const float* __restrict__ d5b, const float* __restrict__ a5,
             const float* __restrict__ d61w, const float* __restrict__ d61b,
             const float* __restrict__ d62w, const float* __restrict__ d62b,
             const float* __restrict__ d63w, const float* __restrict__ d63b,
             float* __restrict__ out) {
    __shared__ float hbuf[4 * 16 * 128];   // partial sums per wave (32 KB)
    __shared__ float hL[16 * 256];         // h after reduce+prelu (16 KB)
    __shared__ float lg[16 * 16];          // head logits
    const int blk = blockIdx.x, tid = threadIdx.x;
    const int w = tid >> 6, lane = tid & 63, q = lane >> 4, l16 = lane & 15;
    const int img = blk * 16 + l16;

    for (int rep = 0; rep < 2; ++rep) {    // two halves of the 256 outputs
        f32x4 z = {0.f, 0.f, 0.f, 0.f};
        f32x4 acc[8];
        #pragma unroll
        for (int nt = 0; nt < 8; ++nt) acc[nt] = z;

        for (int cc = 0; cc < 9; ++cc) {   // this wave's K quarter
            int c = w * 9 + cc;
            int k0 = c * 32 + q * 8;
            s16x8 A = *(const s16x8*)(flat + (unsigned)img * 1152u + k0);
            #pragma unroll
            for (int nt = 0; nt < 8; ++nt) {
                int oc = (rep * 8 + nt) * 16 + l16;
                s16x8 B = *(const s16x8*)(w5 + (unsigned)oc * 1152u + k0);
                acc[nt] = __builtin_amdgcn_mfma_f32_16x16x32_bf16(A, B, acc[nt], 0, 0, 0);
            }
        }
        #pragma unroll
        for (int nt = 0; nt < 8; ++nt)
        #pragma unroll
        for (int r = 0; r < 4; ++r) {
            int row = q * 4 + r;           // image within tile
            hbuf[(w * 16 + row) * 128 + nt * 16 + l16] = acc[nt][r];
        }
        __syncthreads();
        for (int t = tid; t < 2048; t += 256) {
            int oc_h = t & 127, im = t >> 7;
            float s = hbuf[im * 128 + oc_h] + hbuf[(16 + im) * 128 + oc_h]
                    + hbuf[(32 + im) * 128 + oc_h] + hbuf[(48 + im) * 128 + oc_h];
            int oc = rep * 128 + oc_h;
            s += d5b[oc];
            s = s >= 0.f ? s : s * a5[oc];
            hL[im * 256 + oc] = s;
        }
        __syncthreads();
    }

    // heads: thread = (img 0..15, out 0..15); fp32
    {
        int im = tid >> 4, o = tid & 15;
        const float* wrow; float bias;
        if (o < 2)      { wrow = d61w + o * 256;       bias = d61b[o]; }
        else if (o < 6) { wrow = d62w + (o - 2) * 256; bias = d62b[o - 2]; }
        else            { wrow = d63w + (o - 6) * 256; bias = d63b[o - 6]; }
        float s = bias;
        for (int k = 0; k < 256; ++k) s += hL[im * 256 + k] * wrow[k];
        lg[im * 16 + o] = s;
    }
    __syncthreads();
    {
        int im = tid >> 4, o = tid & 15;
        int gimg = blk * 16 + im;
        float v = lg[im * 16 + o];
        if (o >= 2 && o < 6) {
            out[gimg * 4 + (o - 2)] = v;                       // b [N,4]
        } else if (o >= 6) {
            out[8192 + gimg * 10 + (o - 6)] = v;               // c [N,10]
        } else {
            float l0 = lg[im * 16 + 0], l1 = lg[im * 16 + 1];
            float mx = fmaxf(l0, l1);
            float e0 = __expf(l0 - mx), e1 = __expf(l1 - mx);
            out[28672 + gimg * 2 + o] = (o == 0 ? e0 : e1) / (e0 + e1);   // a [N,2]
        }
    }
}

// ---------------------------------------------------------------------------
extern "C" void kernel_launch(void* const* d_in, const int* in_sizes, int n_in,
                              void* d_out, int out_size, void* d_ws, size_t ws_size,
                              hipStream_t stream) {
    (void)in_sizes; (void)n_in; (void)out_size; (void)ws_size;
    const float* x    = (const float*)d_in[0];
    const float* c1w  = (const float*)d_in[1];
    const float* c1b  = (const float*)d_in[2];
    const float* a1   = (const float*)d_in[3];
    const float* c2w  = (const float*)d_in[4];
    const float* c2b  = (const float*)d_in[5];
    const float* a2   = (const float*)d_in[6];
    const float* c3w  = (const float*)d_in[7];
    const float* c3b  = (const float*)d_in[8];
    const float* a3   = (const float*)d_in[9];
    const float* c4w  = (const float*)d_in[10];
    const float* c4b  = (const float*)d_in[11];
    const float* a4   = (const float*)d_in[12];
    const float* d5w  = (const float*)d_in[13];
    const float* d5b  = (const float*)d_in[14];
    const float* a5   = (const float*)d_in[15];
    const float* d61w = (const float*)d_in[16];
    const float* d61b = (const float*)d_in[17];
    const float* d62w = (const float*)d_in[18];
    const float* d62b = (const float*)d_in[19];
    const float* d63w = (const float*)d_in[20];
    const float* d63b = (const float*)d_in[21];

    char* ws = (char*)d_ws;
    // region plan (aliasing by lifetime):
    //   p1    @ 0          : 69,337,088 B   (dead after K2a)
    //   c2buf @ 69,337,088 : 117,440,512 B  (dead after K2b)
    //   p2    @ 0          : 26,214,400 B   (aliases dead p1)
    //   flat  @ 26,214,400 : 4,718,592 B
    //   weights @ 186,777,600 : ~766 KB     -> total ~179 MB
    unsigned short* p1    = (unsigned short*)(ws + 0);
    unsigned short* c2buf = (unsigned short*)(ws + 69337088);
    unsigned short* p2    = (unsigned short*)(ws + 0);
    unsigned short* flat  = (unsigned short*)(ws + 26214400);
    unsigned short* w2    = (unsigned short*)(ws + 186777600);
    unsigned short* w3    = (unsigned short*)(ws + 186814464);
    unsigned short* w4    = (unsigned short*)(ws + 186888192);
    unsigned short* w5    = (unsigned short*)(ws + 186953728);

    k0_prep <<<1496, 256, 0, stream>>>(c2w, c3w, c4w, d5w, w2, w3, w4, w5);
    k1_conv1<<<2048, 256, 0, stream>>>(x, c1w, c1b, a1, p1);
    k2_conv2<<<2048, 256, 0, stream>>>(p1, w2, c2b, a2, c2buf);
    k2_pool <<<2048, 256, 0, stream>>>(c2buf, p2);
    k3_conv34<<<2048, 256, 0, stream>>>(p2, w3, c3b, a3, w4, c4b, a4, flat);
    k5_head <<<128, 256, 0, stream>>>(flat, w5, d5b, a5, d61w, d61b, d62w, d62b,
                                      d63w, d63b, (float*)d_out);
}

// Round 4
// 438.483 us; speedup vs baseline: 8.9567x; 1.3360x over previous
//
#include <hip/hip_runtime.h>
#include <hip/hip_bf16.h>
#include <stdint.h>

typedef short s16x8 __attribute__((ext_vector_type(8)));
typedef unsigned short u16x8 __attribute__((ext_vector_type(8)));
typedef float f32x4 __attribute__((ext_vector_type(4)));

__device__ __forceinline__ unsigned short f2bf(float f) {
    union { float f; unsigned u; } v; v.f = f;
    unsigned u = v.u;
    unsigned r = u + 0x7fffu + ((u >> 16) & 1u);
    return (unsigned short)(r >> 16);
}
__device__ __forceinline__ float bf2f(unsigned short h) {
    union { unsigned u; float f; } v; v.u = ((unsigned)h) << 16;
    return v.f;
}
__device__ __forceinline__ unsigned pkbf(float a, float b) {
    __hip_bfloat162 h = __float22bfloat162_rn(float2{a, b});
    union { __hip_bfloat162 h; unsigned u; } c; c.h = h; return c.u;
}
__device__ __forceinline__ float lo2f(unsigned d) {
    union { unsigned u; float f; } v; v.u = d << 16; return v.f;
}
__device__ __forceinline__ float hi2f(unsigned d) {
    union { unsigned u; float f; } v; v.u = d & 0xffff0000u; return v.f;
}

// ---------------------------------------------------------------------------
// K0: weight repack (fp32 OIHW -> bf16 [kpos][oc][ic]), d5w -> bf16
// ---------------------------------------------------------------------------
__global__ void k0_prep(const float* __restrict__ c2w, const float* __restrict__ c3w,
                        const float* __restrict__ c4w, const float* __restrict__ d5w,
                        unsigned short* __restrict__ w2, unsigned short* __restrict__ w3,
                        unsigned short* __restrict__ w4, unsigned short* __restrict__ w5) {
    int t = blockIdx.x * 256 + threadIdx.x;
    if (t < 18432) {            // w2 [9][64][32] <- c2w [64][32][3][3]
        int kpos = t / 2048, rem = t % 2048, oc = rem / 32, ic = rem % 32;
        w2[t] = f2bf(c2w[(oc * 32 + ic) * 9 + kpos]);
        return;
    }
    t -= 18432;
    if (t < 36864) {            // w3 [9][64][64] <- c3w [64][64][3][3]
        int kpos = t / 4096, rem = t % 4096, oc = rem / 64, ic = rem % 64;
        w3[t] = f2bf(c3w[(oc * 64 + ic) * 9 + kpos]);
        return;
    }
    t -= 36864;
    if (t < 32768) {            // w4 [4][128][64] <- c4w [128][64][2][2]
        int kpos = t / 8192, rem = t % 8192, oc = rem / 64, ic = rem % 64;
        w4[t] = f2bf(c4w[(oc * 64 + ic) * 4 + kpos]);
        return;
    }
    t -= 32768;
    if (t < 294912) w5[t] = f2bf(d5w[t]);   // [256][1152] bf16
}

// ---------------------------------------------------------------------------
// K1 (R4): conv1 3x3 (3->32) + PReLU + maxpool 3x3 s2 ceil -> p1 [n][23][23][32]
// MFMA with OPERAND SWAP: W first (M=32 oc), X second (N=16 px) so each lane's
// C-regs are 4 consecutive oc -> packed b64 epilogue writes.
// x staged PER STRIP (7 rows, hi/lo packed dwords, 4 KB) -> LDS 24.8 KB total
// -> 5 blocks/CU (was 2). Pool vectorized: 8 oc per task, 9 ds_read_b128 with
// immediate offsets, dword->2-float converts, global dwordx4 store.
// 12 strips x 2 pool rows; stage(s) + pool(s-1) share a phase (2 barriers/strip).
// ---------------------------------------------------------------------------
__global__ __launch_bounds__(256, 4)
void k1_conv1(const float* __restrict__ x, const float* __restrict__ c1w,
              const float* __restrict__ c1b, const float* __restrict__ a1,
              unsigned short* __restrict__ p1) {
    __shared__ unsigned xstrip[3 * 7 * 48];      // [ic][7 rows][48] h|l<<16  (4 KB)
    __shared__ unsigned short cbuf[230 * 40];    // [flat px][32 oc + 8 pad]  (18.4 KB)
    __shared__ unsigned short wlds[1024];        // [32 oc][32 k], k>=27 zero (2 KB)
    __shared__ float bls[32], als[32];

    const int n = blockIdx.x, tid = threadIdx.x;
    const int w = tid >> 6, lane = tid & 63, q = lane >> 4, l16 = lane & 15;

    // stage weights [oc][k] (k = ic*9 + ky*3 + kx), zero-pad k 27..31
    for (int t = tid; t < 1024; t += 256) {
        int oc = t >> 5, k = t & 31;
        wlds[t] = (k < 27) ? f2bf(c1w[oc * 27 + k]) : (unsigned short)0;
    }
    if (tid < 32) { bls[tid] = c1b[tid]; als[tid] = a1[tid]; }
    __syncthreads();

    // W fragments (first operand, M-side): m = nt*16 + l16, k = q*8+j
    s16x8 Wf[2];
    #pragma unroll
    for (int nt = 0; nt < 2; ++nt)
        Wf[nt] = *(const s16x8*)(wlds + (nt * 16 + l16) * 32 + q * 8);

    // per-lane bias/alpha for oc = nt*16 + q*4 + r
    float bq[2][4], aq[2][4];
    #pragma unroll
    for (int nt = 0; nt < 2; ++nt)
    #pragma unroll
    for (int r = 0; r < 4; ++r) {
        bq[nt][r] = bls[nt * 16 + q * 4 + r];
        aq[nt][r] = als[nt * 16 + q * 4 + r];
    }

    // invariant gather offsets (dword units within xstrip)
    int off[8];
    #pragma unroll
    for (int j = 0; j < 8; ++j) {
        int k = q * 8 + j;
        int kk = k < 27 ? k : 26;                // k>=27: W is zero there
        int ic = kk / 9, r9 = kk - ic * 9, ky = r9 / 3, kx = r9 - ky * 3;
        off[j] = ic * 336 + ky * 48 + kx;
    }

    // pool for strip sp (nprows pool rows, kymax window rows)
    auto do_pool = [&](int sp, int nprows, int kymax) {
        int ntask = nprows * 92;                 // nprows * 23 px * 4 ocg
        int t = tid;
        if (t < ntask) {
            int ocg = t & 3; unsigned r2 = (unsigned)t >> 2;
            int px = (int)(r2 % 23u), py_l = (int)(r2 / 23u);
            int kxmax = (px == 22) ? 2 : 3;
            int base = (2 * py_l * 46 + 2 * px) * 40 + ocg * 8;
            float m0 = -3e38f, m1 = -3e38f, m2 = -3e38f, m3 = -3e38f;
            float m4 = -3e38f, m5 = -3e38f, m6 = -3e38f, m7 = -3e38f;
            #pragma unroll
            for (int ky = 0; ky < 3; ++ky) {
                if (ky < kymax) {
                    #pragma unroll
                    for (int kx = 0; kx < 3; ++kx) {
                        if (kx < kxmax) {
                            uint4 d = *(const uint4*)&cbuf[base + (ky * 46 + kx) * 40];
                            m0 = fmaxf(m0, lo2f(d.x)); m1 = fmaxf(m1, hi2f(d.x));
                            m2 = fmaxf(m2, lo2f(d.y)); m3 = fmaxf(m3, hi2f(d.y));
                            m4 = fmaxf(m4, lo2f(d.z)); m5 = fmaxf(m5, hi2f(d.z));
                            m6 = fmaxf(m6, lo2f(d.w)); m7 = fmaxf(m7, hi2f(d.w));
                        }
                    }
                }
            }
            uint4 ov;
            ov.x = pkbf(m0, m1); ov.y = pkbf(m2, m3);
            ov.z = pkbf(m4, m5); ov.w = pkbf(m6, m7);
            int py = 2 * sp + py_l;
            *(uint4*)&p1[n * 16928 + (py * 23 + px) * 32 + ocg * 8] = ov;
        }
    };

    for (int s = 0; s < 12; ++s) {
        const int nrows = (s == 11) ? 2 : 5;     // conv rows this strip
        const int P = 46 * nrows;
        const int ntiles = (P + 15) >> 4;
        const int xr0 = 4 * s;                   // first x row

        // phase 1: stage x strip s (+ pool strip s-1)
        for (int t = tid; t < 1008; t += 256) {
            int ic = t / 336, rem = t - ic * 336;
            int rr = rem / 48, col = rem - rr * 48;
            int row = xr0 + rr; if (row > 47) row = 47;
            float f = x[n * 6912 + ic * 2304 + row * 48 + col];
            unsigned short h = f2bf(f);
            unsigned short l = f2bf(f - bf2f(h));
            xstrip[t] = (unsigned)h | ((unsigned)l << 16);
        }
        if (s > 0) do_pool(s - 1, 2, 3);
        __syncthreads();

        // phase 2: conv via MFMA (W x X), 16 px per tile
        for (int T = w; T < ntiles; T += 4) {
            int px = T * 16 + l16;
            int p = px < P ? px : P - 1;
            int ry = p / 46, cx = p - ry * 46;
            int basex = ry * 48 + cx;
            unsigned vv[8];
            #pragma unroll
            for (int j = 0; j < 8; ++j) vv[j] = xstrip[basex + off[j]];
            s16x8 Xh, Xl;
            #pragma unroll
            for (int j = 0; j < 8; ++j) {
                Xh[j] = (short)(vv[j] & 0xffffu);
                Xl[j] = (short)(vv[j] >> 16);
            }
            f32x4 acc[2] = {{0.f,0.f,0.f,0.f},{0.f,0.f,0.f,0.f}};
            #pragma unroll
            for (int nt = 0; nt < 2; ++nt) {
                acc[nt] = __builtin_amdgcn_mfma_f32_16x16x32_bf16(Wf[nt], Xh, acc[nt], 0, 0, 0);
                acc[nt] = __builtin_amdgcn_mfma_f32_16x16x32_bf16(Wf[nt], Xl, acc[nt], 0, 0, 0);
            }
            if (px < P) {
                #pragma unroll
                for (int nt = 0; nt < 2; ++nt) {
                    float v0 = acc[nt][0] + bq[nt][0];
                    float v1 = acc[nt][1] + bq[nt][1];
                    float v2 = acc[nt][2] + bq[nt][2];
                    float v3 = acc[nt][3] + bq[nt][3];
                    v0 = fmaxf(v0, 0.f) + aq[nt][0] * fminf(v0, 0.f);
                    v1 = fmaxf(v1, 0.f) + aq[nt][1] * fminf(v1, 0.f);
                    v2 = fmaxf(v2, 0.f) + aq[nt][2] * fminf(v2, 0.f);
                    v3 = fmaxf(v3, 0.f) + aq[nt][3] * fminf(v3, 0.f);
                    uint2 pk; pk.x = pkbf(v0, v1); pk.y = pkbf(v2, v3);
                    *(uint2*)&cbuf[px * 40 + nt * 16 + q * 4] = pk;
                }
            }
        }
        __syncthreads();
    }
    // tail: pool last strip (1 pool row, conv rows 44,45 -> ky<2)
    do_pool(11, 1, 2);
}

// ---------------------------------------------------------------------------
// K2a: conv2 3x3 (32->64) + PReLU via MFMA 16x16x32 bf16
// M=441(pad448) px, N=64 oc, K=288 (9 chunks: k = kpos*32 + ic)
// ---------------------------------------------------------------------------
__global__ __launch_bounds__(256, 1)
void k2_conv2(const unsigned short* __restrict__ p1, const unsigned short* __restrict__ w2,
              const float* __restrict__ c2b, const float* __restrict__ a2,
              unsigned short* __restrict__ c2buf) {
    __shared__ unsigned short xs[16928];       // [23*23][32] channels-last bf16
    const int n = blockIdx.x, tid = threadIdx.x;

    const float4* src = (const float4*)(p1 + n * 16928);
    for (int t = tid; t < 2116; t += 256) ((float4*)xs)[t] = src[t];
    __syncthreads();

    const int w = tid >> 6, lane = tid & 63, q = lane >> 4, l16 = lane & 15;
    const int ic0 = q * 8;

    // preload all B fragments (9 kpos x 4 n-tiles) from global (L2-hot)
    s16x8 Bf[36];
    #pragma unroll
    for (int kp = 0; kp < 9; ++kp)
    #pragma unroll
    for (int nt = 0; nt < 4; ++nt) {
        int oc = nt * 16 + l16;
        Bf[kp * 4 + nt] = *(const s16x8*)(w2 + (kp * 64 + oc) * 32 + ic0);
    }

    for (int i = 0; i < 7; ++i) {
        int Mt = w * 7 + i;
        int m = Mt * 16 + l16;
        int px = m < 441 ? m : 440;
        int oy = px / 21, ox = px % 21;
        f32x4 z = {0.f, 0.f, 0.f, 0.f};
        f32x4 acc[4];
        #pragma unroll
        for (int nt = 0; nt < 4; ++nt) acc[nt] = z;

        #pragma unroll
        for (int kp = 0; kp < 9; ++kp) {
            int ky = kp / 3, kx = kp % 3;
            s16x8 A = *(const s16x8*)(xs + ((oy + ky) * 23 + ox + kx) * 32 + ic0);
            #pragma unroll
            for (int nt = 0; nt < 4; ++nt)
                acc[nt] = __builtin_amdgcn_mfma_f32_16x16x32_bf16(A, Bf[kp * 4 + nt], acc[nt], 0, 0, 0);
        }
        #pragma unroll
        for (int nt = 0; nt < 4; ++nt) {
            int oc = nt * 16 + l16;
            float bias = c2b[oc], al = a2[oc];
            #pragma unroll
            for (int r = 0; r < 4; ++r) {
                int row = Mt * 16 + q * 4 + r;
                if (row < 441) {
                    float val = acc[nt][r] + bias;
                    val = val >= 0.f ? val : val * al;
                    c2buf[(unsigned)n * 28672u + (unsigned)(row * 64 + oc)] = f2bf(val);
                }
            }
        }
    }
}

// ---------------------------------------------------------------------------
// K2b: maxpool 3x3 s2 (21->10, no pad needed) -> p2 bf16 [n][10][10][64]
// ---------------------------------------------------------------------------
__global__ void k2_pool(const unsigned short* __restrict__ c2buf, unsigned short* __restrict__ p2) {
    const int n = blockIdx.x, tid = threadIdx.x;
    const unsigned short* cbp = c2buf + (unsigned)n * 28672u;
    for (int t = tid; t < 6400; t += 256) {
        int oc = t & 63, r = t >> 6, py = r / 10, pxo = r % 10;
        float m = -3e38f;
        #pragma unroll
        for (int ky = 0; ky < 3; ++ky)
        #pragma unroll
        for (int kx = 0; kx < 3; ++kx)
            m = fmaxf(m, bf2f(cbp[((py * 2 + ky) * 21 + pxo * 2 + kx) * 64 + oc]));
        p2[(unsigned)n * 6400u + t] = f2bf(m);
    }
}

// ---------------------------------------------------------------------------
// K3: conv3 3x3 (64->64)+PReLU (MFMA) -> pool 2x2 -> conv4 2x2 (64->128)+PReLU
//     (MFMA) -> permuted flatten -> flat bf16 [n][1152]
// ---------------------------------------------------------------------------
__global__ __launch_bounds__(256, 2)
void k3_conv34(const unsigned short* __restrict__ p2, const unsigned short* __restrict__ w3,
               const float* __restrict__ c3b, const float* __restrict__ a3,
               const unsigned short* __restrict__ w4, const float* __restrict__ c4b,
               const float* __restrict__ a4, unsigned short* __restrict__ flat) {
    __shared__ unsigned short xs[6400];     // [10*10][64]
    __shared__ unsigned short c3buf[4096];  // [64 px][64 oc]
    __shared__ unsigned short p3[1024];     // [4*4][64]
    const int n = blockIdx.x, tid = threadIdx.x;

    const float4* src = (const float4*)(p2 + n * 6400);
    for (int t = tid; t < 800; t += 256) ((float4*)xs)[t] = src[t];
    __syncthreads();

    const int w = tid >> 6, lane = tid & 63, q = lane >> 4, l16 = lane & 15;

    // conv3: wave w = M-tile w (px = w*16 + l16 over 8x8); K=576: 18 chunks
    {
        int px = w * 16 + l16;
        int oy = px >> 3, ox = px & 7;
        s16x8 Af[18];
        #pragma unroll
        for (int c = 0; c < 18; ++c) {
            int kp = c >> 1, ky = kp / 3, kx = kp % 3;
            int ic0 = (c & 1) * 32 + q * 8;
            Af[c] = *(const s16x8*)(xs + ((oy + ky) * 10 + ox + kx) * 64 + ic0);
        }
        #pragma unroll
        for (int nt = 0; nt < 4; ++nt) {
            int oc = nt * 16 + l16;
            f32x4 acc = {0.f, 0.f, 0.f, 0.f};
            #pragma unroll
            for (int c = 0; c < 18; ++c) {
                int kp = c >> 1;
                int ic0 = (c & 1) * 32 + q * 8;
                s16x8 B = *(const s16x8*)(w3 + (kp * 64 + oc) * 64 + ic0);
                acc = __builtin_amdgcn_mfma_f32_16x16x32_bf16(Af[c], B, acc, 0, 0, 0);
            }
            float bias = c3b[oc], al = a3[oc];
            #pragma unroll
            for (int r = 0; r < 4; ++r) {
                int row = w * 16 + q * 4 + r;   // px 0..63
                float val = acc[r] + bias;
                val = val >= 0.f ? val : val * al;
                c3buf[row * 64 + oc] = f2bf(val);
            }
        }
    }
    __syncthreads();

    // pool3 2x2 s2 (8->4, exact)
    for (int t = tid; t < 1024; t += 256) {
        int oc = t & 63, r = t >> 6, py = r >> 2, pxo = r & 3;
        float m = -3e38f;
        #pragma unroll
        for (int ky = 0; ky < 2; ++ky)
        #pragma unroll
        for (int kx = 0; kx < 2; ++kx)
            m = fmaxf(m, bf2f(c3buf[((py * 2 + ky) * 8 + pxo * 2 + kx) * 64 + oc]));
        p3[t] = f2bf(m);
    }
    __syncthreads();

    // conv4: M=9(pad16) px, N=128 (wave w -> n-tiles w*2, w*2+1), K=256: 8 chunks
    {
        int m = l16, px = m < 9 ? m : 8;
        int oy = px / 3, ox = px % 3;
        s16x8 Af[8];
        #pragma unroll
        for (int c = 0; c < 8; ++c) {
            int kp = c >> 1, ky = kp >> 1, kx = kp & 1;
            int ic0 = (c & 1) * 32 + q * 8;
            Af[c] = *(const s16x8*)(p3 + ((oy + ky) * 4 + ox + kx) * 64 + ic0);
        }
        #pragma unroll
        for (int h = 0; h < 2; ++h) {
            int nt = w * 2 + h, oc = nt * 16 + l16;
            f32x4 acc = {0.f, 0.f, 0.f, 0.f};
            #pragma unroll
            for (int c = 0; c < 8; ++c) {
                int kp = c >> 1;
                int ic0 = (c & 1) * 32 + q * 8;
                s16x8 B = *(const s16x8*)(w4 + (kp * 128 + oc) * 64 + ic0);
                acc = __builtin_amdgcn_mfma_f32_16x16x32_bf16(Af[c], B, acc, 0, 0, 0);
            }
            float bias = c4b[oc], al = a4[oc];
            #pragma unroll
            for (int r = 0; r < 4; ++r) {
                int row = q * 4 + r;
                if (row < 9) {
                    int hy = row / 3, wx = row % 3;
                    float val = acc[r] + bias;
                    val = val >= 0.f ? val : val * al;
                    // torch permute(0,3,2,1).view: idx = (wx*3 + hy)*128 + oc
                    flat[(unsigned)n * 1152u + (wx * 3 + hy) * 128 + oc] = f2bf(val);
                }
            }
        }
    }
}

// ---------------------------------------------------------------------------
// K5: d5 GEMM (MFMA, K split across 4 waves) + bias + PReLU, then 3 heads
// (fp32 dots) + 2-class softmax. Output: b[2048x4] | c[2048x10] | a[2048x2]
// ---------------------------------------------------------------------------
__global__ __launch_bounds__(256, 1)
void k5_head(const unsigned short* __restrict__ flat, const unsigned short* __restrict__ w5,
             const float* __restrict__ d5b, const float* __restrict__ a5,
             const float* __restrict__ d61w, const float* __restrict__ d61b,
             const float* __restrict__ d62w, const float* __restrict__ d62b,
             const float* __restrict__ d63w, const float* __restrict__ d63b,
             float* __restrict__ out) {
    __shared__ float hbuf[4 * 16 * 128];   // partial sums per wave (32 KB)
    __shared__ float hL[16 * 256];         // h after reduce+prelu (16 KB)
    __shared__ float lg[16 * 16];          // head logits
    const int blk = blockIdx.x, tid = threadIdx.x;
    const int w = tid >> 6, lane = tid & 63, q = lane >> 4, l16 = lane & 15;
    const int img = blk * 16 + l16;

    for (int rep = 0; rep < 2; ++rep) {    // two halves of the 256 outputs
        f32x4 z = {0.f, 0.f, 0.f, 0.f};
        f32x4 acc[8];
        #pragma unroll
        for (int nt = 0; nt < 8; ++nt) acc[nt] = z;

        for (int cc = 0; cc < 9; ++cc) {   // this wave's K quarter
            int c = w * 9 + cc;
            int k0 = c * 32 + q * 8;
            s16x8 A = *(const s16x8*)(flat + (unsigned)img * 1152u + k0);
            #pragma unroll
            for (int nt = 0; nt < 8; ++nt) {
                int oc = (rep * 8 + nt) * 16 + l16;
                s16x8 B = *(const s16x8*)(w5 + (unsigned)oc * 1152u + k0);
                acc[nt] = __builtin_amdgcn_mfma_f32_16x16x32_bf16(A, B, acc[nt], 0, 0, 0);
            }
        }
        #pragma unroll
        for (int nt = 0; nt < 8; ++nt)
        #pragma unroll
        for (int r = 0; r < 4; ++r) {
            int row = q * 4 + r;           // image within tile
            hbuf[(w * 16 + row) * 128 + nt * 16 + l16] = acc[nt][r];
        }
        __syncthreads();
        for (int t = tid; t < 2048; t += 256) {
            int oc_h = t & 127, im = t >> 7;
            float s = hbuf[im * 128 + oc_h] + hbuf[(16 + im) * 128 + oc_h]
                    + hbuf[(32 + im) * 128 + oc_h] + hbuf[(48 + im) * 128 + oc_h];
            int oc = rep * 128 + oc_h;
            s += d5b[oc];
            s = s >= 0.f ? s : s * a5[oc];
            hL[im * 256 + oc] = s;
        }
        __syncthreads();
    }

    // heads: thread = (img 0..15, out 0..15); fp32
    {
        int im = tid >> 4, o = tid & 15;
        const float* wrow; float bias;
        if (o < 2)      { wrow = d61w + o * 256;       bias = d61b[o]; }
        else if (o < 6) { wrow = d62w + (o - 2) * 256; bias = d62b[o - 2]; }
        else            { wrow = d63w + (o - 6) * 256; bias = d63b[o - 6]; }
        float s = bias;
        for (int k = 0; k < 256; ++k) s += hL[im * 256 + k] * wrow[k];
        lg[im * 16 + o] = s;
    }
    __syncthreads();
    {
        int im = tid >> 4, o = tid & 15;
        int gimg = blk * 16 + im;
        float v = lg[im * 16 + o];
        if (o >= 2 && o < 6) {
            out[gimg * 4 + (o - 2)] = v;                       // b [N,4]
        } else if (o >= 6) {
            out[8192 + gimg * 10 + (o - 6)] = v;               // c [N,10]
        } else {
            float l0 = lg[im * 16 + 0], l1 = lg[im * 16 + 1];
            float mx = fmaxf(l0, l1);
            float e0 = __expf(l0 - mx), e1 = __expf(l1 - mx);
            out[28672 + gimg * 2 + o] = (o == 0 ? e0 : e1) / (e0 + e1);   // a [N,2]
        }
    }
}

// ---------------------------------------------------------------------------
extern "C" void kernel_launch(void* const* d_in, const int* in_sizes, int n_in,
                              void* d_out, int out_size, void* d_ws, size_t ws_size,
                              hipStream_t stream) {
    (void)in_sizes; (void)n_in; (void)out_size; (void)ws_size;
    const float* x    = (const float*)d_in[0];
    const float* c1w  = (const float*)d_in[1];
    const float* c1b  = (const float*)d_in[2];
    const float* a1   = (const float*)d_in[3];
    const float* c2w  = (const float*)d_in[4];
    const float* c2b  = (const float*)d_in[5];
    const float* a2   = (const float*)d_in[6];
    const float* c3w  = (const float*)d_in[7];
    const float* c3b  = (const float*)d_in[8];
    const float* a3   = (const float*)d_in[9];
    const float* c4w  = (const float*)d_in[10];
    const float* c4b  = (const float*)d_in[11];
    const float* a4   = (const float*)d_in[12];
    const float* d5w  = (const float*)d_in[13];
    const float* d5b  = (const float*)d_in[14];
    const float* a5   = (const float*)d_in[15];
    const float* d61w = (const float*)d_in[16];
    const float* d61b = (const float*)d_in[17];
    const float* d62w = (const float*)d_in[18];
    const float* d62b = (const float*)d_in[19];
    const float* d63w = (const float*)d_in[20];
    const float* d63b = (const float*)d_in[21];

    char* ws = (char*)d_ws;
    // region plan (aliasing by lifetime):
    //   p1    @ 0          : 69,337,088 B   (dead after K2a)
    //   c2buf @ 69,337,088 : 117,440,512 B  (dead after K2b)
    //   p2    @ 0          : 26,214,400 B   (aliases dead p1)
    //   flat  @ 26,214,400 : 4,718,592 B
    //   weights @ 186,777,600 : ~766 KB     -> total ~179 MB
    unsigned short* p1    = (unsigned short*)(ws + 0);
    unsigned short* c2buf = (unsigned short*)(ws + 69337088);
    unsigned short* p2    = (unsigned short*)(ws + 0);
    unsigned short* flat  = (unsigned short*)(ws + 26214400);
    unsigned short* w2    = (unsigned short*)(ws + 186777600);
    unsigned short* w3    = (unsigned short*)(ws + 186814464);
    unsigned short* w4    = (unsigned short*)(ws + 186888192);
    unsigned short* w5    = (unsigned short*)(ws + 186953728);

    k0_prep <<<1496, 256, 0, stream>>>(c2w, c3w, c4w, d5w, w2, w3, w4, w5);
    k1_conv1<<<2048, 256, 0, stream>>>(x, c1w, c1b, a1, p1);
    k2_conv2<<<2048, 256, 0, stream>>>(p1, w2, c2b, a2, c2buf);
    k2_pool <<<2048, 256, 0, stream>>>(c2buf, p2);
    k3_conv34<<<2048, 256, 0, stream>>>(p2, w3, c3b, a3, w4, c4b, a4, flat);
    k5_head <<<128, 256, 0, stream>>>(flat, w5, d5b, a5, d61w, d61b, d62w, d62b,
                                      d63w, d63b, (float*)d_out);
}

// Round 6
// 414.086 us; speedup vs baseline: 9.4844x; 1.0589x over previous
//
#include <hip/hip_runtime.h>
#include <hip/hip_bf16.h>
#include <stdint.h>

typedef short s16x8 __attribute__((ext_vector_type(8)));
typedef unsigned short u16x8 __attribute__((ext_vector_type(8)));
typedef float f32x4 __attribute__((ext_vector_type(4)));

__device__ __forceinline__ unsigned short f2bf(float f) {
    union { float f; unsigned u; } v; v.f = f;
    unsigned u = v.u;
    unsigned r = u + 0x7fffu + ((u >> 16) & 1u);
    return (unsigned short)(r >> 16);
}
__device__ __forceinline__ float bf2f(unsigned short h) {
    union { unsigned u; float f; } v; v.u = ((unsigned)h) << 16;
    return v.f;
}
__device__ __forceinline__ unsigned pkbf(float a, float b) {
    __hip_bfloat162 h = __float22bfloat162_rn(float2{a, b});
    union { __hip_bfloat162 h; unsigned u; } c; c.h = h; return c.u;
}
__device__ __forceinline__ float lo2f(unsigned d) {
    union { unsigned u; float f; } v; v.u = d << 16; return v.f;
}
__device__ __forceinline__ float hi2f(unsigned d) {
    union { unsigned u; float f; } v; v.u = d & 0xffff0000u; return v.f;
}

// ---------------------------------------------------------------------------
// K0: weight repack (fp32 OIHW -> bf16 [kpos][oc][ic]), d5w -> bf16
// ---------------------------------------------------------------------------
__global__ void k0_prep(const float* __restrict__ c2w, const float* __restrict__ c3w,
                        const float* __restrict__ c4w, const float* __restrict__ d5w,
                        unsigned short* __restrict__ w2, unsigned short* __restrict__ w3,
                        unsigned short* __restrict__ w4, unsigned short* __restrict__ w5) {
    int t = blockIdx.x * 256 + threadIdx.x;
    if (t < 18432) {            // w2 [9][64][32] <- c2w [64][32][3][3]
        int kpos = t / 2048, rem = t % 2048, oc = rem / 32, ic = rem % 32;
        w2[t] = f2bf(c2w[(oc * 32 + ic) * 9 + kpos]);
        return;
    }
    t -= 18432;
    if (t < 36864) {            // w3 [9][64][64] <- c3w [64][64][3][3]
        int kpos = t / 4096, rem = t % 4096, oc = rem / 64, ic = rem % 64;
        w3[t] = f2bf(c3w[(oc * 64 + ic) * 9 + kpos]);
        return;
    }
    t -= 36864;
    if (t < 32768) {            // w4 [4][128][64] <- c4w [128][64][2][2]
        int kpos = t / 8192, rem = t % 8192, oc = rem / 64, ic = rem % 64;
        w4[t] = f2bf(c4w[(oc * 64 + ic) * 4 + kpos]);
        return;
    }
    t -= 32768;
    if (t < 294912) w5[t] = f2bf(d5w[t]);   // [256][1152] bf16
}

// ---------------------------------------------------------------------------
// K1 (R4, unchanged): conv1 + PReLU + maxpool -> p1 bf16 [n][23][23][32]
// ---------------------------------------------------------------------------
__global__ __launch_bounds__(256, 4)
void k1_conv1(const float* __restrict__ x, const float* __restrict__ c1w,
              const float* __restrict__ c1b, const float* __restrict__ a1,
              unsigned short* __restrict__ p1) {
    __shared__ unsigned xstrip[3 * 7 * 48];      // [ic][7 rows][48] h|l<<16  (4 KB)
    __shared__ unsigned short cbuf[230 * 40];    // [flat px][32 oc + 8 pad]  (18.4 KB)
    __shared__ unsigned short wlds[1024];        // [32 oc][32 k], k>=27 zero (2 KB)
    __shared__ float bls[32], als[32];

    const int n = blockIdx.x, tid = threadIdx.x;
    const int w = tid >> 6, lane = tid & 63, q = lane >> 4, l16 = lane & 15;

    for (int t = tid; t < 1024; t += 256) {
        int oc = t >> 5, k = t & 31;
        wlds[t] = (k < 27) ? f2bf(c1w[oc * 27 + k]) : (unsigned short)0;
    }
    if (tid < 32) { bls[tid] = c1b[tid]; als[tid] = a1[tid]; }
    __syncthreads();

    s16x8 Wf[2];
    #pragma unroll
    for (int nt = 0; nt < 2; ++nt)
        Wf[nt] = *(const s16x8*)(wlds + (nt * 16 + l16) * 32 + q * 8);

    float bq[2][4], aq[2][4];
    #pragma unroll
    for (int nt = 0; nt < 2; ++nt)
    #pragma unroll
    for (int r = 0; r < 4; ++r) {
        bq[nt][r] = bls[nt * 16 + q * 4 + r];
        aq[nt][r] = als[nt * 16 + q * 4 + r];
    }

    int off[8];
    #pragma unroll
    for (int j = 0; j < 8; ++j) {
        int k = q * 8 + j;
        int kk = k < 27 ? k : 26;
        int ic = kk / 9, r9 = kk - ic * 9, ky = r9 / 3, kx = r9 - ky * 3;
        off[j] = ic * 336 + ky * 48 + kx;
    }

    auto do_pool = [&](int sp, int nprows, int kymax) {
        int ntask = nprows * 92;
        int t = tid;
        if (t < ntask) {
            int ocg = t & 3; unsigned r2 = (unsigned)t >> 2;
            int px = (int)(r2 % 23u), py_l = (int)(r2 / 23u);
            int kxmax = (px == 22) ? 2 : 3;
            int base = (2 * py_l * 46 + 2 * px) * 40 + ocg * 8;
            float m0 = -3e38f, m1 = -3e38f, m2 = -3e38f, m3 = -3e38f;
            float m4 = -3e38f, m5 = -3e38f, m6 = -3e38f, m7 = -3e38f;
            #pragma unroll
            for (int ky = 0; ky < 3; ++ky) {
                if (ky < kymax) {
                    #pragma unroll
                    for (int kx = 0; kx < 3; ++kx) {
                        if (kx < kxmax) {
                            uint4 d = *(const uint4*)&cbuf[base + (ky * 46 + kx) * 40];
                            m0 = fmaxf(m0, lo2f(d.x)); m1 = fmaxf(m1, hi2f(d.x));
                            m2 = fmaxf(m2, lo2f(d.y)); m3 = fmaxf(m3, hi2f(d.y));
                            m4 = fmaxf(m4, lo2f(d.z)); m5 = fmaxf(m5, hi2f(d.z));
                            m6 = fmaxf(m6, lo2f(d.w)); m7 = fmaxf(m7, hi2f(d.w));
                        }
                    }
                }
            }
            uint4 ov;
            ov.x = pkbf(m0, m1); ov.y = pkbf(m2, m3);
            ov.z = pkbf(m4, m5); ov.w = pkbf(m6, m7);
            int py = 2 * sp + py_l;
            *(uint4*)&p1[n * 16928 + (py * 23 + px) * 32 + ocg * 8] = ov;
        }
    };

    for (int s = 0; s < 12; ++s) {
        const int nrows = (s == 11) ? 2 : 5;
        const int P = 46 * nrows;
        const int ntiles = (P + 15) >> 4;
        const int xr0 = 4 * s;

        for (int t = tid; t < 1008; t += 256) {
            int ic = t / 336, rem = t - ic * 336;
            int rr = rem / 48, col = rem - rr * 48;
            int row = xr0 + rr; if (row > 47) row = 47;
            float f = x[n * 6912 + ic * 2304 + row * 48 + col];
            unsigned short h = f2bf(f);
            unsigned short l = f2bf(f - bf2f(h));
            xstrip[t] = (unsigned)h | ((unsigned)l << 16);
        }
        if (s > 0) do_pool(s - 1, 2, 3);
        __syncthreads();

        for (int T = w; T < ntiles; T += 4) {
            int px = T * 16 + l16;
            int p = px < P ? px : P - 1;
            int ry = p / 46, cx = p - ry * 46;
            int basex = ry * 48 + cx;
            unsigned vv[8];
            #pragma unroll
            for (int j = 0; j < 8; ++j) vv[j] = xstrip[basex + off[j]];
            s16x8 Xh, Xl;
            #pragma unroll
            for (int j = 0; j < 8; ++j) {
                Xh[j] = (short)(vv[j] & 0xffffu);
                Xl[j] = (short)(vv[j] >> 16);
            }
            f32x4 acc[2] = {{0.f,0.f,0.f,0.f},{0.f,0.f,0.f,0.f}};
            #pragma unroll
            for (int nt = 0; nt < 2; ++nt) {
                acc[nt] = __builtin_amdgcn_mfma_f32_16x16x32_bf16(Wf[nt], Xh, acc[nt], 0, 0, 0);
                acc[nt] = __builtin_amdgcn_mfma_f32_16x16x32_bf16(Wf[nt], Xl, acc[nt], 0, 0, 0);
            }
            if (px < P) {
                #pragma unroll
                for (int nt = 0; nt < 2; ++nt) {
                    float v0 = acc[nt][0] + bq[nt][0];
                    float v1 = acc[nt][1] + bq[nt][1];
                    float v2 = acc[nt][2] + bq[nt][2];
                    float v3 = acc[nt][3] + bq[nt][3];
                    v0 = fmaxf(v0, 0.f) + aq[nt][0] * fminf(v0, 0.f);
                    v1 = fmaxf(v1, 0.f) + aq[nt][1] * fminf(v1, 0.f);
                    v2 = fmaxf(v2, 0.f) + aq[nt][2] * fminf(v2, 0.f);
                    v3 = fmaxf(v3, 0.f) + aq[nt][3] * fminf(v3, 0.f);
                    uint2 pk; pk.x = pkbf(v0, v1); pk.y = pkbf(v2, v3);
                    *(uint2*)&cbuf[px * 40 + nt * 16 + q * 4] = pk;
                }
            }
        }
        __syncthreads();
    }
    do_pool(11, 1, 2);
}

// ---------------------------------------------------------------------------
// K23 (R6): FUSED conv2+pool2+conv3+pool3+conv4 per image. Eliminates the
// 286 MB HBM round-trip (c2buf 117MBx2 + p2 26MBx2) of the split kernels.
// R5 BUG: staging count was 598 uint4 (= 4784 shorts) but 13 p1 rows are
// 9568 shorts = 1196 uint4 — half of xs was stale poison. Fixed: 1196.
// LDS map:
//   xs:  p1 rows window [13][23][32]            @ 0      (19136 B)
//   c2s: conv2 strip    [231][72] (pad 64->72)  @ 19136  (33264 B)
//   p2s: pooled 10x10   [100][64]               @ 52400  (12800 B)
//   c3buf [64][64] / p3 [16][64] alias dead c2s region.
// Total 65.2 KB LDS -> 2 blocks/CU. 8 barriers. flat is the only HBM output.
// ---------------------------------------------------------------------------
__global__ __launch_bounds__(256, 2)
void k23_fused(const unsigned short* __restrict__ p1, const unsigned short* __restrict__ w2,
               const float* __restrict__ c2b, const float* __restrict__ a2,
               const unsigned short* __restrict__ w3, const float* __restrict__ c3b,
               const float* __restrict__ a3, const unsigned short* __restrict__ w4,
               const float* __restrict__ c4b, const float* __restrict__ a4,
               unsigned short* __restrict__ flat) {
    __shared__ __align__(16) char smem[65200];
    unsigned short* xs    = (unsigned short*)(smem);            // [13][23][32]
    unsigned short* c2s   = (unsigned short*)(smem + 19136);    // [231][72]
    unsigned short* p2s   = (unsigned short*)(smem + 52400);    // [100][64]
    unsigned short* c3buf = (unsigned short*)(smem + 19136);    // alias (8 KB)
    unsigned short* p3    = (unsigned short*)(smem + 27328);    // alias (2 KB)

    const int n = blockIdx.x, tid = threadIdx.x;
    const int w = tid >> 6, lane = tid & 63, q = lane >> 4, l16 = lane & 15;
    const uint4* p1src = (const uint4*)(p1 + n * 16928);

    // conv2 B fragments: [9 kpos][4 nt], oc = nt*16+l16, ic = q*8..q*8+7
    s16x8 Bf[36];
    #pragma unroll
    for (int kp = 0; kp < 9; ++kp)
    #pragma unroll
    for (int nt = 0; nt < 4; ++nt) {
        int oc = nt * 16 + l16;
        Bf[kp * 4 + nt] = *(const s16x8*)(w2 + (kp * 64 + oc) * 32 + q * 8);
    }
    float b2r[4], a2r[4];
    #pragma unroll
    for (int nt = 0; nt < 4; ++nt) { b2r[nt] = c2b[nt * 16 + l16]; a2r[nt] = a2[nt * 16 + l16]; }

    // conv2 for one half (231 px staged in xs), epilogue -> c2s
    auto conv2_half = [&]() {
        for (int T = w; T < 15; T += 4) {
            int m = T * 16 + l16;
            int p = m < 231 ? m : 230;
            int oy = p / 21, ox = p - oy * 21;
            f32x4 acc[4] = {{0.f,0.f,0.f,0.f},{0.f,0.f,0.f,0.f},
                            {0.f,0.f,0.f,0.f},{0.f,0.f,0.f,0.f}};
            #pragma unroll
            for (int kp = 0; kp < 9; ++kp) {
                int ky = kp / 3, kx = kp % 3;
                s16x8 A = *(const s16x8*)(xs + ((oy + ky) * 23 + ox + kx) * 32 + q * 8);
                #pragma unroll
                for (int nt = 0; nt < 4; ++nt)
                    acc[nt] = __builtin_amdgcn_mfma_f32_16x16x32_bf16(A, Bf[kp * 4 + nt], acc[nt], 0, 0, 0);
            }
            #pragma unroll
            for (int nt = 0; nt < 4; ++nt) {
                int oc = nt * 16 + l16;
                #pragma unroll
                for (int r = 0; r < 4; ++r) {
                    int row = T * 16 + q * 4 + r;
                    if (row < 231) {
                        float val = acc[nt][r] + b2r[nt];
                        val = fmaxf(val, 0.f) + a2r[nt] * fminf(val, 0.f);
                        c2s[row * 72 + oc] = f2bf(val);
                    }
                }
            }
        }
    };

    // pool2 for one half: 5 pool rows (py0..py0+4) from c2s local rows 0..10
    auto pool_half = [&](int py0) {
        for (int t = tid; t < 400; t += 256) {
            int ocg = t & 7; int r2 = t >> 3;
            int px = r2 % 10, pyl = r2 / 10;
            int base = (pyl * 2 * 21 + px * 2) * 72 + ocg * 8;
            float m0 = -3e38f, m1 = -3e38f, m2 = -3e38f, m3 = -3e38f;
            float m4 = -3e38f, m5 = -3e38f, m6 = -3e38f, m7 = -3e38f;
            #pragma unroll
            for (int ky = 0; ky < 3; ++ky)
            #pragma unroll
            for (int kx = 0; kx < 3; ++kx) {
                uint4 d = *(const uint4*)&c2s[base + (ky * 21 + kx) * 72];
                m0 = fmaxf(m0, lo2f(d.x)); m1 = fmaxf(m1, hi2f(d.x));
                m2 = fmaxf(m2, lo2f(d.y)); m3 = fmaxf(m3, hi2f(d.y));
                m4 = fmaxf(m4, lo2f(d.z)); m5 = fmaxf(m5, hi2f(d.z));
                m6 = fmaxf(m6, lo2f(d.w)); m7 = fmaxf(m7, hi2f(d.w));
            }
            uint4 ov;
            ov.x = pkbf(m0, m1); ov.y = pkbf(m2, m3);
            ov.z = pkbf(m4, m5); ov.w = pkbf(m6, m7);
            *(uint4*)&p2s[((py0 + pyl) * 10 + px) * 64 + ocg * 8] = ov;
        }
    };

    // phase 1: stage p1 rows 0..12 (13 rows = 9568 shorts = 1196 uint4)
    for (int t = tid; t < 1196; t += 256) ((uint4*)xs)[t] = p1src[t];
    __syncthreads();
    // phase 2: conv2 half A (conv rows 0..10)
    conv2_half();
    __syncthreads();
    // phase 3: pool A (py 0..4) + stage p1 rows 10..22 (offset 920 uint4)
    pool_half(0);
    for (int t = tid; t < 1196; t += 256) ((uint4*)xs)[t] = p1src[920 + t];
    __syncthreads();
    // phase 4: conv2 half B (conv rows 10..20)
    conv2_half();
    __syncthreads();
    // phase 5: pool B (py 5..9)
    pool_half(5);
    __syncthreads();

    // phase 6: conv3 (64 px, K=576: 18 chunks), reads p2s -> c3buf
    {
        int px = w * 16 + l16;
        int oy = px >> 3, ox = px & 7;
        s16x8 Af[18];
        #pragma unroll
        for (int c = 0; c < 18; ++c) {
            int kp = c >> 1, ky = kp / 3, kx = kp % 3;
            int ic0 = (c & 1) * 32 + q * 8;
            Af[c] = *(const s16x8*)(p2s + ((oy + ky) * 10 + ox + kx) * 64 + ic0);
        }
        #pragma unroll
        for (int nt = 0; nt < 4; ++nt) {
            int oc = nt * 16 + l16;
            f32x4 acc = {0.f, 0.f, 0.f, 0.f};
            #pragma unroll
            for (int c = 0; c < 18; ++c) {
                int kp = c >> 1;
                int ic0 = (c & 1) * 32 + q * 8;
                s16x8 B = *(const s16x8*)(w3 + (kp * 64 + oc) * 64 + ic0);
                acc = __builtin_amdgcn_mfma_f32_16x16x32_bf16(Af[c], B, acc, 0, 0, 0);
            }
            float bias = c3b[oc], al = a3[oc];
            #pragma unroll
            for (int r = 0; r < 4; ++r) {
                int row = w * 16 + q * 4 + r;
                float val = acc[r] + bias;
                val = fmaxf(val, 0.f) + al * fminf(val, 0.f);
                c3buf[row * 64 + oc] = f2bf(val);
            }
        }
    }
    __syncthreads();

    // phase 7: pool3 2x2 s2 (8->4) -> p3
    for (int t = tid; t < 1024; t += 256) {
        int oc = t & 63, r = t >> 6, py = r >> 2, pxo = r & 3;
        float m = -3e38f;
        #pragma unroll
        for (int ky = 0; ky < 2; ++ky)
        #pragma unroll
        for (int kx = 0; kx < 2; ++kx)
            m = fmaxf(m, bf2f(c3buf[((py * 2 + ky) * 8 + pxo * 2 + kx) * 64 + oc]));
        p3[t] = f2bf(m);
    }
    __syncthreads();

    // phase 8: conv4 (M=9 pad16, N=128, K=256: 8 chunks) -> permuted flat
    {
        int m = l16, px = m < 9 ? m : 8;
        int oy = px / 3, ox = px % 3;
        s16x8 Af[8];
        #pragma unroll
        for (int c = 0; c < 8; ++c) {
            int kp = c >> 1, ky = kp >> 1, kx = kp & 1;
            int ic0 = (c & 1) * 32 + q * 8;
            Af[c] = *(const s16x8*)(p3 + ((oy + ky) * 4 + ox + kx) * 64 + ic0);
        }
        #pragma unroll
        for (int h = 0; h < 2; ++h) {
            int nt = w * 2 + h, oc = nt * 16 + l16;
            f32x4 acc = {0.f, 0.f, 0.f, 0.f};
            #pragma unroll
            for (int c = 0; c < 8; ++c) {
                int kp = c >> 1;
                int ic0 = (c & 1) * 32 + q * 8;
                s16x8 B = *(const s16x8*)(w4 + (kp * 128 + oc) * 64 + ic0);
                acc = __builtin_amdgcn_mfma_f32_16x16x32_bf16(Af[c], B, acc, 0, 0, 0);
            }
            float bias = c4b[oc], al = a4[oc];
            #pragma unroll
            for (int r = 0; r < 4; ++r) {
                int row = q * 4 + r;
                if (row < 9) {
                    int hy = row / 3, wx = row % 3;
                    float val = acc[r] + bias;
                    val = fmaxf(val, 0.f) + al * fminf(val, 0.f);
                    flat[(unsigned)n * 1152u + (wx * 3 + hy) * 128 + oc] = f2bf(val);
                }
            }
        }
    }
}

// ---------------------------------------------------------------------------
// K5: d5 GEMM (MFMA, K split across 4 waves) + bias + PReLU, then 3 heads
// ---------------------------------------------------------------------------
__global__ __launch_bounds__(256, 1)
void k5_head(const unsigned short* __restrict__ flat, const unsigned short* __restrict__ w5,
             const float* __restrict__ d5b, const float* __restrict__ a5,
             const float* __restrict__ d61w, const float* __restrict__ d61b,
             const float* __restrict__ d62w, const float* __restrict__ d62b,
             const float* __restrict__ d63w, const float* __restrict__ d63b,
             float* __restrict__ out) {
    __shared__ float hbuf[4 * 16 * 128];
    __shared__ float hL[16 * 256];
    __shared__ float lg[16 * 16];
    const int blk = blockIdx.x, tid = threadIdx.x;
    const int w = tid >> 6, lane = tid & 63, q = lane >> 4, l16 = lane & 15;
    const int img = blk * 16 + l16;

    for (int rep = 0; rep < 2; ++rep) {
        f32x4 z = {0.f, 0.f, 0.f, 0.f};
        f32x4 acc[8];
        #pragma unroll
        for (int nt = 0; nt < 8; ++nt) acc[nt] = z;

        for (int cc = 0; cc < 9; ++cc) {
            int c = w * 9 + cc;
            int k0 = c * 32 + q * 8;
            s16x8 A = *(const s16x8*)(flat + (unsigned)img * 1152u + k0);
            #pragma unroll
            for (int nt = 0; nt < 8; ++nt) {
                int oc = (rep * 8 + nt) * 16 + l16;
                s16x8 B = *(const s16x8*)(w5 + (unsigned)oc * 1152u + k0);
                acc[nt] = __builtin_amdgcn_mfma_f32_16x16x32_bf16(A, B, acc[nt], 0, 0, 0);
            }
        }
        #pragma unroll
        for (int nt = 0; nt < 8; ++nt)
        #pragma unroll
        for (int r = 0; r < 4; ++r) {
            int row = q * 4 + r;
            hbuf[(w * 16 + row) * 128 + nt * 16 + l16] = acc[nt][r];
        }
        __syncthreads();
        for (int t = tid; t < 2048; t += 256) {
            int oc_h = t & 127, im = t >> 7;
            float s = hbuf[im * 128 + oc_h] + hbuf[(16 + im) * 128 + oc_h]
                    + hbuf[(32 + im) * 128 + oc_h] + hbuf[(48 + im) * 128 + oc_h];
            int oc = rep * 128 + oc_h;
            s += d5b[oc];
            s = s >= 0.f ? s : s * a5[oc];
            hL[im * 256 + oc] = s;
        }
        __syncthreads();
    }

    {
        int im = tid >> 4, o = tid & 15;
        const float* wrow; float bias;
        if (o < 2)      { wrow = d61w + o * 256;       bias = d61b[o]; }
        else if (o < 6) { wrow = d62w + (o - 2) * 256; bias = d62b[o - 2]; }
        else            { wrow = d63w + (o - 6) * 256; bias = d63b[o - 6]; }
        float s = bias;
        for (int k = 0; k < 256; ++k) s += hL[im * 256 + k] * wrow[k];
        lg[im * 16 + o] = s;
    }
    __syncthreads();
    {
        int im = tid >> 4, o = tid & 15;
        int gimg = blk * 16 + im;
        float v = lg[im * 16 + o];
        if (o >= 2 && o < 6) {
            out[gimg * 4 + (o - 2)] = v;
        } else if (o >= 6) {
            out[8192 + gimg * 10 + (o - 6)] = v;
        } else {
            float l0 = lg[im * 16 + 0], l1 = lg[im * 16 + 1];
            float mx = fmaxf(l0, l1);
            float e0 = __expf(l0 - mx), e1 = __expf(l1 - mx);
            out[28672 + gimg * 2 + o] = (o == 0 ? e0 : e1) / (e0 + e1);
        }
    }
}

// ---------------------------------------------------------------------------
extern "C" void kernel_launch(void* const* d_in, const int* in_sizes, int n_in,
                              void* d_out, int out_size, void* d_ws, size_t ws_size,
                              hipStream_t stream) {
    (void)in_sizes; (void)n_in; (void)out_size; (void)ws_size;
    const float* x    = (const float*)d_in[0];
    const float* c1w  = (const float*)d_in[1];
    const float* c1b  = (const float*)d_in[2];
    const float* a1   = (const float*)d_in[3];
    const float* c2w  = (const float*)d_in[4];
    const float* c2b  = (const float*)d_in[5];
    const float* a2   = (const float*)d_in[6];
    const float* c3w  = (const float*)d_in[7];
    const float* c3b  = (const float*)d_in[8];
    const float* a3   = (const float*)d_in[9];
    const float* c4w  = (const float*)d_in[10];
    const float* c4b  = (const float*)d_in[11];
    const float* a4   = (const float*)d_in[12];
    const float* d5w  = (const float*)d_in[13];
    const float* d5b  = (const float*)d_in[14];
    const float* a5   = (const float*)d_in[15];
    const float* d61w = (const float*)d_in[16];
    const float* d61b = (const float*)d_in[17];
    const float* d62w = (const float*)d_in[18];
    const float* d62b = (const float*)d_in[19];
    const float* d63w = (const float*)d_in[20];
    const float* d63b = (const float*)d_in[21];

    char* ws = (char*)d_ws;
    // region plan:
    //   p1    @ 0          : 69,337,088 B  (live through k23_fused)
    //   flat  @ 69,337,088 : 4,718,592 B   (must not overlap p1 — k23 reads
    //                                       p1 while writing flat)
    //   weights @ 186,777,600 : ~766 KB
    unsigned short* p1    = (unsigned short*)(ws + 0);
    unsigned short* flat  = (unsigned short*)(ws + 69337088);
    unsigned short* w2    = (unsigned short*)(ws + 186777600);
    unsigned short* w3    = (unsigned short*)(ws + 186814464);
    unsigned short* w4    = (unsigned short*)(ws + 186888192);
    unsigned short* w5    = (unsigned short*)(ws + 186953728);

    k0_prep  <<<1496, 256, 0, stream>>>(c2w, c3w, c4w, d5w, w2, w3, w4, w5);
    k1_conv1 <<<2048, 256, 0, stream>>>(x, c1w, c1b, a1, p1);
    k23_fused<<<2048, 256, 0, stream>>>(p1, w2, c2b, a2, w3, c3b, a3, w4, c4b, a4, flat);
    k5_head  <<<128, 256, 0, stream>>>(flat, w5, d5b, a5, d61w, d61b, d62w, d62b,
                                       d63w, d63b, (float*)d_out);
}